// Round 1
// baseline (15619.865 us; speedup 1.0000x reference)
//
#include <hip/hip_runtime.h>

#define BATCH 2048

// ---------------------------------------------------------------- reductions
__device__ inline float wave_reduce(float v) {
#pragma unroll
  for (int o = 32; o > 0; o >>= 1) v += __shfl_down(v, o, 64);
  return v;
}

__device__ inline void block_reduce_atomic(float s, float q, float* dsum, float* dsq) {
  __shared__ float red[8];
  s = wave_reduce(s);
  q = wave_reduce(q);
  int lane = threadIdx.x & 63, wid = threadIdx.x >> 6;
  if (lane == 0) { red[wid] = s; red[4 + wid] = q; }
  __syncthreads();
  if (threadIdx.x == 0) {
    float S = red[0] + red[1] + red[2] + red[3];
    float Q = red[4] + red[5] + red[6] + red[7];
    atomicAdd(dsum, S);
    atomicAdd(dsq, Q);
  }
}

// -------------------------------------------------- conv1 + bias + relu + bn1 stats
// grid: BATCH*32 blocks (b,co), block 256 = 16x16 spatial
__global__ __launch_bounds__(256) void k_conv1(
    const float* __restrict__ x, const float* __restrict__ w,
    const float* __restrict__ bias, float* __restrict__ out,
    float* __restrict__ dsum, float* __restrict__ dsq) {
  int blk = blockIdx.x;
  int co = blk & 31;
  int b  = blk >> 5;
  int t  = threadIdx.x;
  int ho = t >> 4, wo = t & 15;
  const float* xb = x + (size_t)b * 324;  // 18*18
  float wv[9];
#pragma unroll
  for (int i = 0; i < 9; i++) wv[i] = w[co * 9 + i];
  float acc = bias[co];
#pragma unroll
  for (int ki = 0; ki < 3; ki++)
#pragma unroll
    for (int kj = 0; kj < 3; kj++)
      acc = fmaf(xb[(ho + ki) * 18 + wo + kj], wv[ki * 3 + kj], acc);
  acc = fmaxf(acc, 0.0f);
  out[(size_t)blk * 256 + t] = acc;
  block_reduce_atomic(acc, acc * acc, dsum + co, dsq + co);
}

// ------------------------------------------------------------ bn finalize
__global__ void k_bnfin(const float* __restrict__ dsum, const float* __restrict__ dsq,
                        const float* __restrict__ g, const float* __restrict__ beta,
                        float* __restrict__ scale, float* __restrict__ shift,
                        int C, float invN) {
  int c = threadIdx.x;
  if (c < C) {
    float m = dsum[c] * invN;
    float v = dsq[c] * invN - m * m;
    float sc = rsqrtf(v + 1e-5f) * g[c];
    scale[c] = sc;
    shift[c] = beta[c] - m * sc;
  }
}

// ------------------------------------------------------------ offset convs
// thread per output element of (BATCH,18,HO,WO); BN applied on read; zero pad.
template <int CIN, int H, int W, int STRIDE, int HO, int WO>
__global__ __launch_bounds__(256) void k_offconv(
    const float* __restrict__ in, const float* __restrict__ scale,
    const float* __restrict__ shift, const float* __restrict__ w,
    const float* __restrict__ bias, float* __restrict__ out) {
  constexpr int HW = H * W;
  int idx = blockIdx.x * 256 + threadIdx.x;
  if (idx >= BATCH * 18 * HO * WO) return;
  int wo = idx % WO;
  int tmp = idx / WO;
  int ho = tmp % HO; tmp /= HO;
  int co = tmp % 18;
  int b  = tmp / 18;
  const float* inb = in + (size_t)b * CIN * HW;
  float acc = bias[co];
  for (int ci = 0; ci < CIN; ci++) {
    float sc = scale[ci], sh = shift[ci];
    const float* wp = w + ((size_t)co * CIN + ci) * 9;
#pragma unroll
    for (int ki = 0; ki < 3; ki++) {
      int y = ho * STRIDE - 1 + ki;
      if (y < 0 || y >= H) continue;
#pragma unroll
      for (int kj = 0; kj < 3; kj++) {
        int xx = wo * STRIDE - 1 + kj;
        if (xx < 0 || xx >= W) continue;
        acc = fmaf(fmaf(inb[ci * HW + y * W + xx], sc, sh), wp[ki * 3 + kj], acc);
      }
    }
  }
  out[idx] = acc;
}

// ------------------------------------------------------------ deform conv
// block per batch image; whole BN'd input image + offsets staged in LDS.
// thread -> (spatial s, group of CO_PER output channels). relu on store.
template <int CIN, int H, int W, int STRIDE, int HO, int WO, int COUT>
__global__ __launch_bounds__(256) void k_dconv(
    const float* __restrict__ in, const float* __restrict__ scale,
    const float* __restrict__ shift, const float* __restrict__ off,
    const float* __restrict__ w, float* __restrict__ out) {
  constexpr int S = HO * WO;
  constexpr int GROUPS = 256 / S;
  constexpr int CO_PER = COUT / GROUPS;
  constexpr int HW = H * W;
  static_assert(S * GROUPS == 256 && CO_PER * GROUPS == COUT, "geometry");
  __shared__ float tile[CIN * HW];
  __shared__ float offs[18 * S];
  int b = blockIdx.x;
  int t = threadIdx.x;
  const float* inb = in + (size_t)b * CIN * HW;
  for (int i = t; i < CIN * HW; i += 256) {
    int ci = i / HW;
    tile[i] = fmaf(inb[i], scale[ci], shift[ci]);
  }
  const float* ofb = off + (size_t)b * 18 * S;
  for (int i = t; i < 18 * S; i += 256) offs[i] = ofb[i];
  __syncthreads();

  int s   = t % S;
  int co0 = (t / S) * CO_PER;
  int ho = s / WO, wo = s % WO;
  float acc[CO_PER];
#pragma unroll
  for (int i = 0; i < CO_PER; i++) acc[i] = 0.0f;

#pragma unroll
  for (int k = 0; k < 9; k++) {
    int ki = k / 3, kj = k % 3;
    float dy = offs[(2 * k) * S + s];
    float dx = offs[(2 * k + 1) * S + s];
    float py = (float)(ho * STRIDE - 1 + ki) + dy;
    float px = (float)(wo * STRIDE - 1 + kj) + dx;
    float y0f = floorf(py), x0f = floorf(px);
    float wy = py - y0f, wx = px - x0f;
    int y0 = (int)y0f, x0 = (int)x0f;
    int y1 = y0 + 1, x1 = x0 + 1;
    float w00 = (1.0f - wy) * (1.0f - wx);
    float w01 = (1.0f - wy) * wx;
    float w10 = wy * (1.0f - wx);
    float w11 = wy * wx;
    bool vy0 = (unsigned)y0 < (unsigned)H;
    bool vy1 = (unsigned)y1 < (unsigned)H;
    bool vx0 = (unsigned)x0 < (unsigned)W;
    bool vx1 = (unsigned)x1 < (unsigned)W;
    w00 = (vy0 && vx0) ? w00 : 0.0f;
    w01 = (vy0 && vx1) ? w01 : 0.0f;
    w10 = (vy1 && vx0) ? w10 : 0.0f;
    w11 = (vy1 && vx1) ? w11 : 0.0f;
    int yc0 = min(max(y0, 0), H - 1) * W;
    int yc1 = min(max(y1, 0), H - 1) * W;
    int xc0 = min(max(x0, 0), W - 1);
    int xc1 = min(max(x1, 0), W - 1);
    int i00 = yc0 + xc0, i01 = yc0 + xc1, i10 = yc1 + xc0, i11 = yc1 + xc1;
    const float* wk = w + (size_t)co0 * CIN * 9 + k;
    for (int ci = 0; ci < CIN; ci++) {
      const float* tb = tile + ci * HW;
      float val = w00 * tb[i00] + w01 * tb[i01] + w10 * tb[i10] + w11 * tb[i11];
#pragma unroll
      for (int c = 0; c < CO_PER; c++)
        acc[c] = fmaf(wk[(size_t)(c * CIN + ci) * 9], val, acc[c]);
    }
  }
  float* ob = out + (size_t)b * COUT * S;
#pragma unroll
  for (int c = 0; c < CO_PER; c++)
    ob[(co0 + c) * S + s] = fmaxf(acc[c], 0.0f);
}

// ------------------------------------------------------------ bn stats over (B,spatial) per channel
template <int C, int S, int BB>
__global__ __launch_bounds__(256) void k_stats(
    const float* __restrict__ h, float* __restrict__ dsum, float* __restrict__ dsq) {
  int c  = blockIdx.x % C;
  int b0 = (blockIdx.x / C) * BB;
  float s = 0.0f, q = 0.0f;
  for (int i = threadIdx.x; i < BB * S; i += 256) {
    int b = b0 + i / S;
    float v = h[((size_t)b * C + c) * S + (i % S)];
    s += v;
    q = fmaf(v, v, q);
  }
  block_reduce_atomic(s, q, dsum + c, dsq + c);
}

// ------------------------------------------------------------ pool + fc
__global__ __launch_bounds__(128) void k_poolfc(
    const float* __restrict__ h4, const float* __restrict__ scale,
    const float* __restrict__ shift, const float* __restrict__ fcw,
    const float* __restrict__ fcb, float* __restrict__ out) {
  __shared__ float pooled[128];
  int b = blockIdx.x;
  int c = threadIdx.x;
  const float* hb = h4 + (size_t)b * 128 * 16;
  float sm = 0.0f;
#pragma unroll
  for (int s = 0; s < 16; s++) sm += hb[c * 16 + s];
  pooled[c] = fmaf(sm * (1.0f / 16.0f), scale[c], shift[c]);
  __syncthreads();
  if (c < 10) {
    float acc = fcb[c];
    for (int i = 0; i < 128; i++) acc = fmaf(pooled[i], fcw[c * 128 + i], acc);
    out[(size_t)b * 10 + c] = acc;
  }
}

// ---------------------------------------------------------------- launch
extern "C" void kernel_launch(void* const* d_in, const int* in_sizes, int n_in,
                              void* d_out, int out_size, void* d_ws, size_t ws_size,
                              hipStream_t stream) {
  const float* x       = (const float*)d_in[0];
  const float* conv1_w = (const float*)d_in[1];
  const float* conv1_b = (const float*)d_in[2];
  const float* bn1_g   = (const float*)d_in[3];
  const float* bn1_b   = (const float*)d_in[4];
  const float* off1_w  = (const float*)d_in[5];
  const float* off1_b  = (const float*)d_in[6];
  const float* dc1_w   = (const float*)d_in[7];
  const float* bn2_g   = (const float*)d_in[8];
  const float* bn2_b   = (const float*)d_in[9];
  const float* off2_w  = (const float*)d_in[10];
  const float* off2_b  = (const float*)d_in[11];
  const float* dc2_w   = (const float*)d_in[12];
  const float* bn3_g   = (const float*)d_in[13];
  const float* bn3_b   = (const float*)d_in[14];
  const float* off3_w  = (const float*)d_in[15];
  const float* off3_b  = (const float*)d_in[16];
  const float* dc3_w   = (const float*)d_in[17];
  const float* bn4_g   = (const float*)d_in[18];
  const float* bn4_b   = (const float*)d_in[19];
  const float* fc_w    = (const float*)d_in[20];
  const float* fc_b    = (const float*)d_in[21];
  float* out = (float*)d_out;

  float* wsf = (float*)d_ws;
  // bufA: h1 (2048*32*256) then h3 (2048*128*64) -- both 16777216 floats
  float* h1 = wsf;
  float* h3 = wsf;
  // bufB: h2 (2048*64*64 = 8388608 floats) then h4 (2048*128*16 = 4194304)
  float* h2 = wsf + 16777216;
  float* h4 = wsf + 16777216;
  // offsets buffer (max 2048*18*64 = 2359296 floats)
  float* offb = wsf + 16777216 + 8388608;
  // stats: 16 arrays x 128 floats
  float* sb = wsf + 16777216 + 8388608 + 2359296;
  float* sum1 = sb + 0,    *sq1 = sb + 128,  *sc1 = sb + 256,  *sh1 = sb + 384;
  float* sum2 = sb + 512,  *sq2 = sb + 640,  *sc2 = sb + 768,  *sh2 = sb + 896;
  float* sum3 = sb + 1024, *sq3 = sb + 1152, *sc3 = sb + 1280, *sh3 = sb + 1408;
  float* sum4 = sb + 1536, *sq4 = sb + 1664, *sc4 = sb + 1792, *sh4 = sb + 1920;

  hipMemsetAsync(sb, 0, 2048 * sizeof(float), stream);

  // stage 1
  k_conv1<<<BATCH * 32, 256, 0, stream>>>(x, conv1_w, conv1_b, h1, sum1, sq1);
  k_bnfin<<<1, 128, 0, stream>>>(sum1, sq1, bn1_g, bn1_b, sc1, sh1, 32, 1.0f / 524288.0f);
  k_offconv<32, 16, 16, 2, 8, 8><<<(BATCH * 18 * 64 + 255) / 256, 256, 0, stream>>>(
      h1, sc1, sh1, off1_w, off1_b, offb);
  k_dconv<32, 16, 16, 2, 8, 8, 64><<<BATCH, 256, 0, stream>>>(
      h1, sc1, sh1, offb, dc1_w, h2);

  // stage 2
  k_stats<64, 64, 128><<<64 * 16, 256, 0, stream>>>(h2, sum2, sq2);
  k_bnfin<<<1, 128, 0, stream>>>(sum2, sq2, bn2_g, bn2_b, sc2, sh2, 64, 1.0f / 131072.0f);
  k_offconv<64, 8, 8, 1, 8, 8><<<(BATCH * 18 * 64 + 255) / 256, 256, 0, stream>>>(
      h2, sc2, sh2, off2_w, off2_b, offb);
  k_dconv<64, 8, 8, 1, 8, 8, 128><<<BATCH, 256, 0, stream>>>(
      h2, sc2, sh2, offb, dc2_w, h3);

  // stage 3
  k_stats<128, 64, 128><<<128 * 16, 256, 0, stream>>>(h3, sum3, sq3);
  k_bnfin<<<1, 128, 0, stream>>>(sum3, sq3, bn3_g, bn3_b, sc3, sh3, 128, 1.0f / 131072.0f);
  k_offconv<128, 8, 8, 2, 4, 4><<<(BATCH * 18 * 16 + 255) / 256, 256, 0, stream>>>(
      h3, sc3, sh3, off3_w, off3_b, offb);
  k_dconv<128, 8, 8, 2, 4, 4, 128><<<BATCH, 256, 0, stream>>>(
      h3, sc3, sh3, offb, dc3_w, h4);

  // stage 4
  k_stats<128, 16, 128><<<128 * 16, 256, 0, stream>>>(h4, sum4, sq4);
  k_bnfin<<<1, 128, 0, stream>>>(sum4, sq4, bn4_g, bn4_b, sc4, sh4, 128, 1.0f / 32768.0f);
  k_poolfc<<<BATCH, 128, 0, stream>>>(h4, sc4, sh4, fc_w, fc_b, out);
}

// Round 2
// 1664.824 us; speedup vs baseline: 9.3823x; 9.3823x over previous
//
#include <hip/hip_runtime.h>

#define BATCH 2048

// ---------------------------------------------------------------- reductions
__device__ inline float wave_reduce(float v) {
#pragma unroll
  for (int o = 32; o > 0; o >>= 1) v += __shfl_down(v, o, 64);
  return v;
}

__device__ inline void block_reduce_atomic(float s, float q, float* dsum, float* dsq) {
  __shared__ float red[8];
  s = wave_reduce(s);
  q = wave_reduce(q);
  int lane = threadIdx.x & 63, wid = threadIdx.x >> 6;
  if (lane == 0) { red[wid] = s; red[4 + wid] = q; }
  __syncthreads();
  if (threadIdx.x == 0) {
    atomicAdd(dsum, red[0] + red[1] + red[2] + red[3]);
    atomicAdd(dsq, red[4] + red[5] + red[6] + red[7]);
  }
}

// -------------------------------------------------- conv1 + bias + relu + bn1 stats
__global__ __launch_bounds__(256) void k_conv1(
    const float* __restrict__ x, const float* __restrict__ w,
    const float* __restrict__ bias, float* __restrict__ out,
    float* __restrict__ dsum, float* __restrict__ dsq) {
  int blk = blockIdx.x;
  int co = blk & 31;
  int b  = blk >> 5;
  int t  = threadIdx.x;
  int ho = t >> 4, wo = t & 15;
  const float* xb = x + (size_t)b * 324;  // 18*18
  float wv[9];
#pragma unroll
  for (int i = 0; i < 9; i++) wv[i] = w[co * 9 + i];
  float acc = bias[co];
#pragma unroll
  for (int ki = 0; ki < 3; ki++)
#pragma unroll
    for (int kj = 0; kj < 3; kj++)
      acc = fmaf(xb[(ho + ki) * 18 + wo + kj], wv[ki * 3 + kj], acc);
  acc = fmaxf(acc, 0.0f);
  out[(size_t)blk * 256 + t] = acc;
  block_reduce_atomic(acc, acc * acc, dsum + co, dsq + co);
}

// ------------------------------------------------------------ bn finalize
__global__ void k_bnfin(const float* __restrict__ dsum, const float* __restrict__ dsq,
                        const float* __restrict__ g, const float* __restrict__ beta,
                        float* __restrict__ scale, float* __restrict__ shift,
                        int C, float invN) {
  int c = threadIdx.x;
  if (c < C) {
    float m = dsum[c] * invN;
    float v = dsq[c] * invN - m * m;
    float sc = rsqrtf(v + 1e-5f) * g[c];
    scale[c] = sc;
    shift[c] = beta[c] - m * sc;
  }
}

// ------------------------------------------------------------ weight transposes
// dc weights (CO,CIN,3,3) -> [k][ci][co]; off weights (18,CIN,3,3) -> [k][ci][18]
__global__ __launch_bounds__(256) void k_prep(
    const float* __restrict__ dc1, const float* __restrict__ dc2,
    const float* __restrict__ dc3, const float* __restrict__ ow1,
    const float* __restrict__ ow2, const float* __restrict__ ow3,
    float* __restrict__ wt1, float* __restrict__ wt2, float* __restrict__ wt3,
    float* __restrict__ w0t1, float* __restrict__ w0t2, float* __restrict__ w0t3) {
  int idx = blockIdx.x * 256 + threadIdx.x;
  const float* in; float* out; int CO, CI;
  if (idx < 18432)        { in = dc1; out = wt1;  CO = 64;  CI = 32;  }
  else if (idx < 92160)   { idx -= 18432;  in = dc2; out = wt2;  CO = 128; CI = 64;  }
  else if (idx < 239616)  { idx -= 92160;  in = dc3; out = wt3;  CO = 128; CI = 128; }
  else if (idx < 244800)  { idx -= 239616; in = ow1; out = w0t1; CO = 18;  CI = 32;  }
  else if (idx < 255168)  { idx -= 244800; in = ow2; out = w0t2; CO = 18;  CI = 64;  }
  else if (idx < 275904)  { idx -= 255168; in = ow3; out = w0t3; CO = 18;  CI = 128; }
  else return;
  int co = idx % CO;
  int r  = idx / CO;
  int ci = r % CI;
  int k  = r / CI;
  out[idx] = in[(co * CI + ci) * 9 + k];
}

// ------------------------------------------------------------ fused offsetconv + deform conv
// block = 1 image. Phase 0: offset conv into LDS. Per k: phase A bilinear val slice
// into LDS, phase B register-blocked GEMM (weights coalesced from global/L2).
template <int CIN, int H, int W, int STRIDE, int HO, int WO, int COUT>
__global__ __launch_bounds__(256, 2) void k_dconv(
    const float* __restrict__ in, const float* __restrict__ scale,
    const float* __restrict__ shift, const float* __restrict__ w0t,
    const float* __restrict__ obias, const float* __restrict__ wt,
    float* __restrict__ out) {
  constexpr int S    = HO * WO;
  constexpr int HW   = H * W;
  constexpr int CP   = CIN + 4;      // padded tile row (floats)
  constexpr int REPS = 256 / S;      // ci-split replicas
  constexpr int CPR  = CIN / REPS;   // ci per replica
  constexpr int CB   = 8;            // co per thread
  constexpr int NCO_G = COUT / CB;
  constexpr int NSG  = 256 / NCO_G;
  constexpr int SB   = S / NSG;      // s per thread
  constexpr int SP   = S + 4;        // padded val row
  static_assert(REPS * S == 256 && NSG * SB == S && CPR % 4 == 0, "geometry");

  __shared__ float tile[HW * CP];
  __shared__ float offs[18 * S];
  __shared__ float ubuf[4608];       // union: phase0 partials / val slice

  int b = blockIdx.x;
  int t = threadIdx.x;

  // ---- stage BN'd input, transposed to [pos][ci]
  const float* inb = in + (size_t)b * CIN * HW;
  for (int i = t; i < CIN * HW; i += 256) {
    int ci = i / HW, pos = i % HW;
    tile[pos * CP + ci] = fmaf(inb[i], scale[ci], shift[ci]);
  }
  __syncthreads();

  // ---- phase 0: offset conv (3x3, stride STRIDE, pad 1), 18 channels
  {
    int s   = t & (S - 1);
    int rep = t / S;
    if constexpr (S == 64) rep = __builtin_amdgcn_readfirstlane(t >> 6);
    int ho = s / WO, wo = s % WO;
    int ci0 = rep * CPR;
    float a0[18];
#pragma unroll
    for (int c = 0; c < 18; c++) a0[c] = 0.0f;
    for (int k = 0; k < 9; k++) {
      int y = ho * STRIDE - 1 + k / 3;
      int x = wo * STRIDE - 1 + k % 3;
      bool valid = ((unsigned)y < (unsigned)H) && ((unsigned)x < (unsigned)W);
      int pos = valid ? y * W + x : 0;
#pragma unroll
      for (int g = 0; g < CPR / 4; g++) {
        int ci = ci0 + g * 4;
        float4 f = *(const float4*)&tile[pos * CP + ci];
        float tv[4] = {f.x, f.y, f.z, f.w};
        if (!valid) { tv[0] = tv[1] = tv[2] = tv[3] = 0.0f; }
        int base = (k * CIN + ci) * 18;
        if constexpr (S == 64) base = __builtin_amdgcn_readfirstlane(base);
        const float* wp = w0t + base;
#pragma unroll
      for (int j = 0; j < 4; j++)
#pragma unroll
        for (int c = 0; c < 18; c++)
          a0[c] = fmaf(tv[j], wp[j * 18 + c], a0[c]);
      }
    }
#pragma unroll
    for (int c = 0; c < 18; c++) ubuf[c * 256 + t] = a0[c];  // rep*S+s == t
  }
  __syncthreads();
  for (int o = t; o < 18 * S; o += 256) {
    int co = o / S, s = o % S;
    float v = obias[co];
#pragma unroll
    for (int r = 0; r < REPS; r++) v += ubuf[co * 256 + r * S + s];
    offs[o] = v;
  }

  // ---- main loop over 9 taps
  int s_a = t & (S - 1);
  int rep_a = t / S;
  int ho_a = s_a / WO, wo_a = s_a % WO;
  int cg = t % NCO_G, sg = t / NCO_G;
  int s0 = sg * SB, co0 = cg * CB;
  float acc[SB][CB];
#pragma unroll
  for (int i = 0; i < SB; i++)
#pragma unroll
    for (int j = 0; j < CB; j++) acc[i][j] = 0.0f;

  for (int k = 0; k < 9; k++) {
    __syncthreads();  // ubuf free, offs stable
    // ---- phase A: bilinear val slice -> ubuf[ci][s]
    {
      float dy = offs[(2 * k) * S + s_a];
      float dx = offs[(2 * k + 1) * S + s_a];
      float py = (float)(ho_a * STRIDE - 1 + k / 3) + dy;
      float px = (float)(wo_a * STRIDE - 1 + k % 3) + dx;
      float y0f = floorf(py), x0f = floorf(px);
      float wy = py - y0f, wx = px - x0f;
      int y0 = (int)y0f, x0 = (int)x0f, y1 = y0 + 1, x1 = x0 + 1;
      float w00 = (1.0f - wy) * (1.0f - wx);
      float w01 = (1.0f - wy) * wx;
      float w10 = wy * (1.0f - wx);
      float w11 = wy * wx;
      bool vy0 = (unsigned)y0 < (unsigned)H, vy1 = (unsigned)y1 < (unsigned)H;
      bool vx0 = (unsigned)x0 < (unsigned)W, vx1 = (unsigned)x1 < (unsigned)W;
      w00 = (vy0 && vx0) ? w00 : 0.0f;
      w01 = (vy0 && vx1) ? w01 : 0.0f;
      w10 = (vy1 && vx0) ? w10 : 0.0f;
      w11 = (vy1 && vx1) ? w11 : 0.0f;
      int yc0 = min(max(y0, 0), H - 1) * W, yc1 = min(max(y1, 0), H - 1) * W;
      int xc0 = min(max(x0, 0), W - 1),     xc1 = min(max(x1, 0), W - 1);
      int p00 = (yc0 + xc0) * CP, p01 = (yc0 + xc1) * CP;
      int p10 = (yc1 + xc0) * CP, p11 = (yc1 + xc1) * CP;
      int ci0 = rep_a * CPR;
#pragma unroll
      for (int g = 0; g < CPR / 4; g++) {
        int ci = ci0 + g * 4;
        float4 f00 = *(const float4*)&tile[p00 + ci];
        float4 f01 = *(const float4*)&tile[p01 + ci];
        float4 f10 = *(const float4*)&tile[p10 + ci];
        float4 f11 = *(const float4*)&tile[p11 + ci];
        float v00[4] = {f00.x, f00.y, f00.z, f00.w};
        float v01[4] = {f01.x, f01.y, f01.z, f01.w};
        float v10[4] = {f10.x, f10.y, f10.z, f10.w};
        float v11[4] = {f11.x, f11.y, f11.z, f11.w};
#pragma unroll
        for (int j = 0; j < 4; j++) {
          float val = w00 * v00[j] + w01 * v01[j] + w10 * v10[j] + w11 * v11[j];
          ubuf[(ci + j) * SP + s_a] = val;
        }
      }
    }
    __syncthreads();
    // ---- phase B: GEMM slice, weights coalesced from global (L1/L2-resident)
    const float* wrow = wt + (size_t)k * CIN * COUT + co0;
#pragma unroll 2
    for (int ci = 0; ci < CIN; ci++) {
      float wv[CB];
      float4 fa = *(const float4*)&wrow[0];
      float4 fb = *(const float4*)&wrow[4];
      wv[0] = fa.x; wv[1] = fa.y; wv[2] = fa.z; wv[3] = fa.w;
      wv[4] = fb.x; wv[5] = fb.y; wv[6] = fb.z; wv[7] = fb.w;
      float vs[SB];
      if constexpr (SB == 4) {
        float4 f = *(const float4*)&ubuf[ci * SP + s0];
        vs[0] = f.x; vs[1] = f.y; vs[2] = f.z; vs[3] = f.w;
      } else if constexpr (SB == 2) {
        float2 f = *(const float2*)&ubuf[ci * SP + s0];
        vs[0] = f.x; vs[1] = f.y;
      } else {
        vs[0] = ubuf[ci * SP + s0];
      }
#pragma unroll
      for (int i = 0; i < SB; i++)
#pragma unroll
        for (int j = 0; j < CB; j++) acc[i][j] = fmaf(vs[i], wv[j], acc[i][j]);
      wrow += COUT;
    }
  }

  // ---- epilogue: relu + store out[b][co][s]
  float* ob = out + (size_t)b * COUT * S;
#pragma unroll
  for (int j = 0; j < CB; j++) {
    if constexpr (SB == 4) {
      float4 f = make_float4(fmaxf(acc[0][j], 0.0f), fmaxf(acc[1][j], 0.0f),
                             fmaxf(acc[2][j], 0.0f), fmaxf(acc[3][j], 0.0f));
      *(float4*)&ob[(co0 + j) * S + s0] = f;
    } else if constexpr (SB == 2) {
      float2 f = make_float2(fmaxf(acc[0][j], 0.0f), fmaxf(acc[1][j], 0.0f));
      *(float2*)&ob[(co0 + j) * S + s0] = f;
    } else {
      ob[(co0 + j) * S + s0] = fmaxf(acc[0][j], 0.0f);
    }
  }
}

// ------------------------------------------------------------ bn stats per channel
template <int C, int S, int BB>
__global__ __launch_bounds__(256) void k_stats(
    const float* __restrict__ h, float* __restrict__ dsum, float* __restrict__ dsq) {
  int c  = blockIdx.x % C;
  int b0 = (blockIdx.x / C) * BB;
  float s = 0.0f, q = 0.0f;
  for (int i = threadIdx.x; i < BB * S; i += 256) {
    int b = b0 + i / S;
    float v = h[((size_t)b * C + c) * S + (i % S)];
    s += v;
    q = fmaf(v, v, q);
  }
  block_reduce_atomic(s, q, dsum + c, dsq + c);
}

// ------------------------------------------------------------ pool + fc
__global__ __launch_bounds__(128) void k_poolfc(
    const float* __restrict__ h4, const float* __restrict__ scale,
    const float* __restrict__ shift, const float* __restrict__ fcw,
    const float* __restrict__ fcb, float* __restrict__ out) {
  __shared__ float pooled[128];
  int b = blockIdx.x;
  int c = threadIdx.x;
  const float* hb = h4 + (size_t)b * 128 * 16;
  float sm = 0.0f;
#pragma unroll
  for (int s = 0; s < 16; s++) sm += hb[c * 16 + s];
  pooled[c] = fmaf(sm * (1.0f / 16.0f), scale[c], shift[c]);
  __syncthreads();
  if (c < 10) {
    float acc = fcb[c];
#pragma unroll
    for (int i = 0; i < 128; i++) acc = fmaf(pooled[i], fcw[c * 128 + i], acc);
    out[(size_t)b * 10 + c] = acc;
  }
}

// ---------------------------------------------------------------- launch
extern "C" void kernel_launch(void* const* d_in, const int* in_sizes, int n_in,
                              void* d_out, int out_size, void* d_ws, size_t ws_size,
                              hipStream_t stream) {
  const float* x       = (const float*)d_in[0];
  const float* conv1_w = (const float*)d_in[1];
  const float* conv1_b = (const float*)d_in[2];
  const float* bn1_g   = (const float*)d_in[3];
  const float* bn1_b   = (const float*)d_in[4];
  const float* off1_w  = (const float*)d_in[5];
  const float* off1_b  = (const float*)d_in[6];
  const float* dc1_w   = (const float*)d_in[7];
  const float* bn2_g   = (const float*)d_in[8];
  const float* bn2_b   = (const float*)d_in[9];
  const float* off2_w  = (const float*)d_in[10];
  const float* off2_b  = (const float*)d_in[11];
  const float* dc2_w   = (const float*)d_in[12];
  const float* bn3_g   = (const float*)d_in[13];
  const float* bn3_b   = (const float*)d_in[14];
  const float* off3_w  = (const float*)d_in[15];
  const float* off3_b  = (const float*)d_in[16];
  const float* dc3_w   = (const float*)d_in[17];
  const float* bn4_g   = (const float*)d_in[18];
  const float* bn4_b   = (const float*)d_in[19];
  const float* fc_w    = (const float*)d_in[20];
  const float* fc_b    = (const float*)d_in[21];
  float* out = (float*)d_out;

  float* wsf = (float*)d_ws;
  // region A: h1 (2048*32*256) / h3 (2048*128*64) alias — 16777216 floats
  float* h1 = wsf;
  float* h3 = wsf;
  // region B: h2 (2048*64*64) / h4 (2048*128*16) alias — 8388608 floats
  float* h2 = wsf + 16777216;
  float* h4 = wsf + 16777216;
  // transposed weights
  float* wbase = wsf + 16777216 + 8388608;
  float* wt1  = wbase;            // 18432
  float* wt2  = wbase + 18432;    // 73728
  float* wt3  = wbase + 92160;    // 147456
  float* w0t1 = wbase + 239616;   // 5184
  float* w0t2 = wbase + 244800;   // 10368
  float* w0t3 = wbase + 255168;   // 20736
  // stats
  float* sb = wbase + 275904;
  float* sum1 = sb + 0,    *sq1 = sb + 128,  *sc1 = sb + 256,  *sh1 = sb + 384;
  float* sum2 = sb + 512,  *sq2 = sb + 640,  *sc2 = sb + 768,  *sh2 = sb + 896;
  float* sum3 = sb + 1024, *sq3 = sb + 1152, *sc3 = sb + 1280, *sh3 = sb + 1408;
  float* sum4 = sb + 1536, *sq4 = sb + 1664, *sc4 = sb + 1792, *sh4 = sb + 1920;

  hipMemsetAsync(sb, 0, 2048 * sizeof(float), stream);
  k_prep<<<1078, 256, 0, stream>>>(dc1_w, dc2_w, dc3_w, off1_w, off2_w, off3_w,
                                   wt1, wt2, wt3, w0t1, w0t2, w0t3);

  // stage 1
  k_conv1<<<BATCH * 32, 256, 0, stream>>>(x, conv1_w, conv1_b, h1, sum1, sq1);
  k_bnfin<<<1, 128, 0, stream>>>(sum1, sq1, bn1_g, bn1_b, sc1, sh1, 32, 1.0f / 524288.0f);
  k_dconv<32, 16, 16, 2, 8, 8, 64><<<BATCH, 256, 0, stream>>>(
      h1, sc1, sh1, w0t1, off1_b, wt1, h2);

  // stage 2
  k_stats<64, 64, 128><<<64 * 16, 256, 0, stream>>>(h2, sum2, sq2);
  k_bnfin<<<1, 128, 0, stream>>>(sum2, sq2, bn2_g, bn2_b, sc2, sh2, 64, 1.0f / 131072.0f);
  k_dconv<64, 8, 8, 1, 8, 8, 128><<<BATCH, 256, 0, stream>>>(
      h2, sc2, sh2, w0t2, off2_b, wt2, h3);

  // stage 3
  k_stats<128, 64, 128><<<128 * 16, 256, 0, stream>>>(h3, sum3, sq3);
  k_bnfin<<<1, 128, 0, stream>>>(sum3, sq3, bn3_g, bn3_b, sc3, sh3, 128, 1.0f / 131072.0f);
  k_dconv<128, 8, 8, 2, 4, 4, 128><<<BATCH, 256, 0, stream>>>(
      h3, sc3, sh3, w0t3, off3_b, wt3, h4);

  // stage 4
  k_stats<128, 16, 128><<<128 * 16, 256, 0, stream>>>(h4, sum4, sq4);
  k_bnfin<<<1, 128, 0, stream>>>(sum4, sq4, bn4_g, bn4_b, sc4, sh4, 128, 1.0f / 32768.0f);
  k_poolfc<<<BATCH, 128, 0, stream>>>(h4, sc4, sh4, fc_w, fc_b, out);
}

// Round 5
// 741.980 us; speedup vs baseline: 21.0516x; 2.2438x over previous
//
#include <hip/hip_runtime.h>

#define BATCH 2048

typedef __attribute__((ext_vector_type(8))) short bf16x8;
typedef __attribute__((ext_vector_type(4))) float f32x4;

__device__ inline float bf2f(unsigned short u) {
  union { unsigned int i; float f; } v;
  v.i = ((unsigned int)u) << 16;
  return v.f;
}
__device__ inline unsigned short f2bf(float f) {
  union { float f; unsigned int i; } v;
  v.f = f;
  unsigned int r = v.i + 0x7FFFu + ((v.i >> 16) & 1u);
  return (unsigned short)(r >> 16);
}

// -------------------------------------------------- conv1 + bias + relu + bn1 stats
// out layout: [b][pos(256)][co(32)]
__global__ __launch_bounds__(256) void k_conv1(
    const float* __restrict__ x, const float* __restrict__ w,
    const float* __restrict__ bias, float* __restrict__ out,
    float* __restrict__ dsum, float* __restrict__ dsq) {
  __shared__ float xs[324];
  __shared__ float wsm[288];
  __shared__ float red[512];
  int b = blockIdx.x, t = threadIdx.x;
  const float* xb = x + (size_t)b * 324;
  for (int i = t; i < 324; i += 256) xs[i] = xb[i];
  for (int i = t; i < 288; i += 256) wsm[i] = w[i];
  __syncthreads();
  int co = t & 31, pp = t >> 5;
  float wv[9];
#pragma unroll
  for (int k = 0; k < 9; k++) wv[k] = wsm[co * 9 + k];
  float bb = bias[co];
  float sp = 0.0f, qp = 0.0f;
  float* ob = out + (size_t)b * 8192;
  for (int i = 0; i < 32; i++) {
    int pos = (i << 3) + pp;
    int ho = pos >> 4, wo = pos & 15;
    float a = bb;
#pragma unroll
    for (int ki = 0; ki < 3; ki++)
#pragma unroll
      for (int kj = 0; kj < 3; kj++)
        a = fmaf(xs[(ho + ki) * 18 + wo + kj], wv[ki * 3 + kj], a);
    a = fmaxf(a, 0.0f);
    ob[pos * 32 + co] = a;
    sp += a;
    qp = fmaf(a, a, qp);
  }
  red[t] = sp;
  red[256 + t] = qp;
  __syncthreads();
  if (t < 32) {
    float S = 0.0f, Q = 0.0f;
#pragma unroll
    for (int r = 0; r < 8; r++) {
      S += red[r * 32 + t];
      Q += red[256 + r * 32 + t];
    }
    atomicAdd(dsum + t, S);
    atomicAdd(dsq + t, Q);
  }
}

// ------------------------------------------------------------ bn finalize
__global__ void k_bnfin(const float* __restrict__ dsum, const float* __restrict__ dsq,
                        const float* __restrict__ g, const float* __restrict__ beta,
                        float* __restrict__ scale, float* __restrict__ shift,
                        int C, float invN) {
  int c = threadIdx.x;
  if (c < C) {
    float m = dsum[c] * invN;
    float v = dsq[c] * invN - m * m;
    float sc = rsqrtf(v + 1e-5f) * g[c];
    scale[c] = sc;
    shift[c] = beta[c] - m * sc;
  }
}

// ------------------------------------------------------------ weight prep
// dc weights -> split-bf16 MFMA B-fragment packs (hi & lo): [tap][ks][ct][lane][8]
//   ci = ks*32 + (lane>>4)*8 + j ; co = ct*16 + (lane&15)
// off weights -> fp32 [k][ci][18]
__global__ __launch_bounds__(256) void k_prep(
    const float* __restrict__ dc1, const float* __restrict__ dc2,
    const float* __restrict__ dc3, const float* __restrict__ ow1,
    const float* __restrict__ ow2, const float* __restrict__ ow3,
    unsigned short* __restrict__ wp1h, unsigned short* __restrict__ wp1l,
    unsigned short* __restrict__ wp2h, unsigned short* __restrict__ wp2l,
    unsigned short* __restrict__ wp3h, unsigned short* __restrict__ wp3l,
    float* __restrict__ w0t1, float* __restrict__ w0t2, float* __restrict__ w0t3) {
  int idx = blockIdx.x * 256 + threadIdx.x;
  if (idx < 239616) {
    int e = idx;
    const float* src; unsigned short *dh, *dl; int CIN, NCT, KS;
    if (e < 18432)      { src = dc1; dh = wp1h; dl = wp1l; CIN = 32;  NCT = 4; KS = 1; }
    else if (e < 92160) { e -= 18432; src = dc2; dh = wp2h; dl = wp2l; CIN = 64;  NCT = 8; KS = 2; }
    else                { e -= 92160; src = dc3; dh = wp3h; dl = wp3l; CIN = 128; NCT = 8; KS = 4; }
    int j = e & 7, lane = (e >> 3) & 63;
    int rest = e >> 9;
    int ct = rest % NCT; rest /= NCT;
    int ks = rest % KS;
    int tap = rest / KS;
    int ci = ks * 32 + ((lane >> 4) << 3) + j;
    int co = ct * 16 + (lane & 15);
    float wv = src[((size_t)co * CIN + ci) * 9 + tap];
    unsigned short h = f2bf(wv);
    dh[e] = h;
    dl[e] = f2bf(wv - bf2f(h));
  } else if (idx < 275904) {
    int e = idx - 239616;
    const float* in; float* out; int CI;
    if (e < 5184)       { in = ow1; out = w0t1; CI = 32; }
    else if (e < 15552) { e -= 5184;  in = ow2; out = w0t2; CI = 64; }
    else                { e -= 15552; in = ow3; out = w0t3; CI = 128; }
    int co = e % 18;
    int r = e / 18;
    int ci = r % CI;
    int k = r / CI;
    out[e] = in[((size_t)co * CI + ci) * 9 + k];
  }
}

// ------------------------------------------------------------ fused offsetconv + deform conv
// fp32 tile/offsets; split-bf16 A & B; triple-MFMA accumulation in fp32.
// in/out layout [b][pos][ci]. Per block = 1 image.
template <int CIN, int H, int W, int STRIDE, int HO, int WO, int COUT>
__global__ __launch_bounds__(256, 4) void k_dconv(
    const float* __restrict__ in, const float* __restrict__ scale,
    const float* __restrict__ shift, const float* __restrict__ w0t,
    const float* __restrict__ obias, const unsigned short* __restrict__ wph,
    const unsigned short* __restrict__ wpl, float* __restrict__ out) {
  constexpr int S   = HO * WO;
  constexpr int HW  = H * W;
  constexpr int CP  = CIN + 4;      // fp32 tile row stride
  constexpr int AP  = CIN + 8;      // A-buffer row stride (ushorts)
  constexpr int LOFF = S * AP;      // lo-plane offset in abuf
  constexpr int REPS = 256 / S;
  constexpr int CPR  = CIN / REPS;
  constexpr int NRT = S / 16;       // row tiles (4,4,1)
  constexpr int NCT = COUT / 16;    // col tiles (4,8,8)
  constexpr int KS  = CIN / 32;     // k-steps per tap
  constexpr int CT_PER = (NRT == 4) ? NCT : NCT / 4;
  static_assert(REPS * S == 256 && CPR % 4 == 0, "geometry");

  __shared__ float tile[HW * CP];
  __shared__ float offs[18 * S];
  __shared__ unsigned short abuf[2 * S * AP];

  int b = blockIdx.x, t = threadIdx.x;

  // ---- stage BN'd input as fp32 [pos][ci]
  const float* inb = in + (size_t)b * CIN * HW;
  for (int i = t; i < HW * CIN / 4; i += 256) {
    int pos = i / (CIN / 4);
    int c4 = (i % (CIN / 4)) * 4;
    float4 v = *(const float4*)&inb[pos * CIN + c4];
    float4 sc = *(const float4*)&scale[c4];
    float4 sh = *(const float4*)&shift[c4];
    float4 o;
    o.x = fmaf(v.x, sc.x, sh.x);
    o.y = fmaf(v.y, sc.y, sh.y);
    o.z = fmaf(v.z, sc.z, sh.z);
    o.w = fmaf(v.w, sc.w, sh.w);
    *(float4*)&tile[pos * CP + c4] = o;
  }
  // init offs with bias
  for (int o = t; o < 18 * S; o += 256) offs[o] = obias[o / S];
  __syncthreads();

  // ---- phase 0: offset conv (3x3, stride STRIDE, pad 1) -> atomic into offs
  {
    int s = t & (S - 1);
    int rep = t / S;
    if constexpr (S == 64) rep = __builtin_amdgcn_readfirstlane(t >> 6);
    int ho = s / WO, wo = s % WO;
    int ci0 = rep * CPR;
    float a0[18];
#pragma unroll
    for (int c = 0; c < 18; c++) a0[c] = 0.0f;
    for (int k = 0; k < 9; k++) {
      int y = ho * STRIDE - 1 + k / 3;
      int x = wo * STRIDE - 1 + k % 3;
      bool valid = ((unsigned)y < (unsigned)H) && ((unsigned)x < (unsigned)W);
      int pos = valid ? y * W + x : 0;
#pragma unroll
      for (int g = 0; g < CPR / 4; g++) {
        int ci = ci0 + g * 4;
        float4 f = *(const float4*)&tile[pos * CP + ci];
        float tv[4] = {f.x, f.y, f.z, f.w};
        if (!valid) { tv[0] = tv[1] = tv[2] = tv[3] = 0.0f; }
        int base = (k * CIN + ci) * 18;
        if constexpr (S == 64) base = __builtin_amdgcn_readfirstlane(base);
        const float* wp = w0t + base;
#pragma unroll
        for (int j = 0; j < 4; j++)
#pragma unroll
          for (int c = 0; c < 18; c++)
            a0[c] = fmaf(tv[j], wp[j * 18 + c], a0[c]);
      }
    }
#pragma unroll
    for (int c = 0; c < 18; c++) atomicAdd(&offs[c * S + s], a0[c]);
  }

  // ---- main loop over 9 taps: phase A bilinear->split-bf16 A slice, phase B MFMA
  int s_a = t & (S - 1);
  int rep_a = t / S;
  int ho_a = s_a / WO, wo_a = s_a % WO;
  int wv = t >> 6, lane = t & 63;
  int rt = (NRT == 4) ? wv : 0;
  int ct0 = (NRT == 4) ? 0 : wv * CT_PER;
  f32x4 acc[CT_PER];
#pragma unroll
  for (int ct = 0; ct < CT_PER; ct++) acc[ct] = (f32x4){0.f, 0.f, 0.f, 0.f};

  for (int k = 0; k < 9; k++) {
    __syncthreads();  // offs ready (k=0) / abuf free (k>0)
    {
      float dy = offs[(2 * k) * S + s_a];
      float dx = offs[(2 * k + 1) * S + s_a];
      float py = (float)(ho_a * STRIDE - 1 + k / 3) + dy;
      float px = (float)(wo_a * STRIDE - 1 + k % 3) + dx;
      float y0f = floorf(py), x0f = floorf(px);
      float wy = py - y0f, wx = px - x0f;
      int y0 = (int)y0f, x0 = (int)x0f, y1 = y0 + 1, x1 = x0 + 1;
      float w00 = (1.0f - wy) * (1.0f - wx);
      float w01 = (1.0f - wy) * wx;
      float w10 = wy * (1.0f - wx);
      float w11 = wy * wx;
      bool vy0 = (unsigned)y0 < (unsigned)H, vy1 = (unsigned)y1 < (unsigned)H;
      bool vx0 = (unsigned)x0 < (unsigned)W, vx1 = (unsigned)x1 < (unsigned)W;
      w00 = (vy0 && vx0) ? w00 : 0.0f;
      w01 = (vy0 && vx1) ? w01 : 0.0f;
      w10 = (vy1 && vx0) ? w10 : 0.0f;
      w11 = (vy1 && vx1) ? w11 : 0.0f;
      int yc0 = min(max(y0, 0), H - 1) * W, yc1 = min(max(y1, 0), H - 1) * W;
      int xc0 = min(max(x0, 0), W - 1),     xc1 = min(max(x1, 0), W - 1);
      int p00 = (yc0 + xc0) * CP, p01 = (yc0 + xc1) * CP;
      int p10 = (yc1 + xc0) * CP, p11 = (yc1 + xc1) * CP;
      int ci0 = rep_a * CPR;
#pragma unroll
      for (int g = 0; g < CPR / 4; g++) {
        int ci = ci0 + g * 4;
        float4 f00 = *(const float4*)&tile[p00 + ci];
        float4 f01 = *(const float4*)&tile[p01 + ci];
        float4 f10 = *(const float4*)&tile[p10 + ci];
        float4 f11 = *(const float4*)&tile[p11 + ci];
        float v0 = w00 * f00.x + w01 * f01.x + w10 * f10.x + w11 * f11.x;
        float v1 = w00 * f00.y + w01 * f01.y + w10 * f10.y + w11 * f11.y;
        float v2 = w00 * f00.z + w01 * f01.z + w10 * f10.z + w11 * f11.z;
        float v3 = w00 * f00.w + w01 * f01.w + w10 * f10.w + w11 * f11.w;
        ushort4 h, l;
        h.x = f2bf(v0); l.x = f2bf(v0 - bf2f(h.x));
        h.y = f2bf(v1); l.y = f2bf(v1 - bf2f(h.y));
        h.z = f2bf(v2); l.z = f2bf(v2 - bf2f(h.z));
        h.w = f2bf(v3); l.w = f2bf(v3 - bf2f(h.w));
        *(ushort4*)&abuf[s_a * AP + ci] = h;
        *(ushort4*)&abuf[LOFF + s_a * AP + ci] = l;
      }
    }
    __syncthreads();
    const unsigned short* wkh = wph + (size_t)k * KS * NCT * 512;
    const unsigned short* wkl = wpl + (size_t)k * KS * NCT * 512;
    int rrow = rt * 16 + (lane & 15);
    int acol = (lane >> 4) << 3;
#pragma unroll
    for (int ks = 0; ks < KS; ks++) {
      bf16x8 ah = *(const bf16x8*)&abuf[rrow * AP + ks * 32 + acol];
      bf16x8 al = *(const bf16x8*)&abuf[LOFF + rrow * AP + ks * 32 + acol];
#pragma unroll
      for (int ct = 0; ct < CT_PER; ct++) {
        const bf16x8 bh = *(const bf16x8*)&wkh[((ks * NCT + ct0 + ct) * 64 + lane) * 8];
        const bf16x8 bl = *(const bf16x8*)&wkl[((ks * NCT + ct0 + ct) * 64 + lane) * 8];
        acc[ct] = __builtin_amdgcn_mfma_f32_16x16x32_bf16(ah, bh, acc[ct], 0, 0, 0);
        acc[ct] = __builtin_amdgcn_mfma_f32_16x16x32_bf16(al, bh, acc[ct], 0, 0, 0);
        acc[ct] = __builtin_amdgcn_mfma_f32_16x16x32_bf16(ah, bl, acc[ct], 0, 0, 0);
      }
    }
  }

  // ---- epilogue: relu + store out[b][s][co]  (C-frag: col=lane&15, row=(lane>>4)*4+r)
  float* ob = out + (size_t)b * S * COUT;
#pragma unroll
  for (int ct = 0; ct < CT_PER; ct++) {
    int co = (ct0 + ct) * 16 + (lane & 15);
    int sr = rt * 16 + ((lane >> 4) << 2);
#pragma unroll
    for (int r = 0; r < 4; r++)
      ob[(sr + r) * COUT + co] = fmaxf(acc[ct][r], 0.0f);
  }
}

// ------------------------------------------------------------ bn stats, layout [row][C]
template <int C, int RPB>
__global__ __launch_bounds__(256) void k_stats(
    const float* __restrict__ h, float* __restrict__ dsum, float* __restrict__ dsq) {
  constexpr int CG = C / 4;
  constexpr int R = 256 / CG;
  __shared__ float red[256 * 8];
  int t = threadIdx.x;
  int c4 = (t % CG) * 4, r = t / CG;
  int row0 = blockIdx.x * RPB;
  float s0 = 0, s1 = 0, s2 = 0, s3 = 0, q0 = 0, q1 = 0, q2 = 0, q3 = 0;
  for (int row = row0 + r; row < row0 + RPB; row += R) {
    float4 v = *(const float4*)&h[(size_t)row * C + c4];
    s0 += v.x; s1 += v.y; s2 += v.z; s3 += v.w;
    q0 = fmaf(v.x, v.x, q0); q1 = fmaf(v.y, v.y, q1);
    q2 = fmaf(v.z, v.z, q2); q3 = fmaf(v.w, v.w, q3);
  }
  float* rp = red + t * 8;
  rp[0] = s0; rp[1] = s1; rp[2] = s2; rp[3] = s3;
  rp[4] = q0; rp[5] = q1; rp[6] = q2; rp[7] = q3;
  __syncthreads();
  if (t < CG) {
#pragma unroll 4
    for (int rr = 1; rr < R; rr++) {
      const float* op = red + (t + rr * CG) * 8;
      s0 += op[0]; s1 += op[1]; s2 += op[2]; s3 += op[3];
      q0 += op[4]; q1 += op[5]; q2 += op[6]; q3 += op[7];
    }
    atomicAdd(dsum + c4 + 0, s0); atomicAdd(dsum + c4 + 1, s1);
    atomicAdd(dsum + c4 + 2, s2); atomicAdd(dsum + c4 + 3, s3);
    atomicAdd(dsq + c4 + 0, q0);  atomicAdd(dsq + c4 + 1, q1);
    atomicAdd(dsq + c4 + 2, q2);  atomicAdd(dsq + c4 + 3, q3);
  }
}

// ------------------------------------------------------------ pool + fc  (h4: [b][s][128])
__global__ __launch_bounds__(128) void k_poolfc(
    const float* __restrict__ h4, const float* __restrict__ scale,
    const float* __restrict__ shift, const float* __restrict__ fcw,
    const float* __restrict__ fcb, float* __restrict__ out) {
  __shared__ float pooled[128];
  int b = blockIdx.x;
  int c = threadIdx.x;
  const float* hb = h4 + (size_t)b * 2048;
  float sm = 0.0f;
#pragma unroll
  for (int s = 0; s < 16; s++) sm += hb[s * 128 + c];
  pooled[c] = fmaf(sm * (1.0f / 16.0f), scale[c], shift[c]);
  __syncthreads();
  if (c < 10) {
    float acc = fcb[c];
#pragma unroll
    for (int i = 0; i < 128; i++) acc = fmaf(pooled[i], fcw[c * 128 + i], acc);
    out[(size_t)b * 10 + c] = acc;
  }
}

// ---------------------------------------------------------------- launch
extern "C" void kernel_launch(void* const* d_in, const int* in_sizes, int n_in,
                              void* d_out, int out_size, void* d_ws, size_t ws_size,
                              hipStream_t stream) {
  const float* x       = (const float*)d_in[0];
  const float* conv1_w = (const float*)d_in[1];
  const float* conv1_b = (const float*)d_in[2];
  const float* bn1_g   = (const float*)d_in[3];
  const float* bn1_b   = (const float*)d_in[4];
  const float* off1_w  = (const float*)d_in[5];
  const float* off1_b  = (const float*)d_in[6];
  const float* dc1_w   = (const float*)d_in[7];
  const float* bn2_g   = (const float*)d_in[8];
  const float* bn2_b   = (const float*)d_in[9];
  const float* off2_w  = (const float*)d_in[10];
  const float* off2_b  = (const float*)d_in[11];
  const float* dc2_w   = (const float*)d_in[12];
  const float* bn3_g   = (const float*)d_in[13];
  const float* bn3_b   = (const float*)d_in[14];
  const float* off3_w  = (const float*)d_in[15];
  const float* off3_b  = (const float*)d_in[16];
  const float* dc3_w   = (const float*)d_in[17];
  const float* bn4_g   = (const float*)d_in[18];
  const float* bn4_b   = (const float*)d_in[19];
  const float* fc_w    = (const float*)d_in[20];
  const float* fc_b    = (const float*)d_in[21];
  float* out = (float*)d_out;

  float* wsf = (float*)d_ws;
  // region A: h1 [2048][256][32] / h3 [2048][64][128] alias — 16777216 floats
  float* h1 = wsf;
  float* h3 = wsf;
  // region B: h2 [2048][64][64] / h4 [2048][16][128] alias — 8388608 floats
  float* h2 = wsf + 16777216;
  float* h4 = wsf + 16777216;
  float* wbase = wsf + 25165824;
  unsigned short* wp1h = (unsigned short*)wbase;   // each dc pack: hi then lo
  unsigned short* wp1l = wp1h + 18432;
  unsigned short* wp2h = wp1l + 18432;
  unsigned short* wp2l = wp2h + 73728;
  unsigned short* wp3h = wp2l + 73728;
  unsigned short* wp3l = wp3h + 147456;            // total 479232 ushorts = 239616 floats
  float* w0t1 = wbase + 239616;                    // 5184 floats
  float* w0t2 = w0t1 + 5184;                       // 10368
  float* w0t3 = w0t2 + 10368;                      // 20736
  float* sb   = wbase + 239616 + 36288;
  float* sum1 = sb + 0,    *sq1 = sb + 128,  *sc1 = sb + 256,  *sh1 = sb + 384;
  float* sum2 = sb + 512,  *sq2 = sb + 640,  *sc2 = sb + 768,  *sh2 = sb + 896;
  float* sum3 = sb + 1024, *sq3 = sb + 1152, *sc3 = sb + 1280, *sh3 = sb + 1408;
  float* sum4 = sb + 1536, *sq4 = sb + 1664, *sc4 = sb + 1792, *sh4 = sb + 1920;

  hipMemsetAsync(sb, 0, 2048 * sizeof(float), stream);
  k_prep<<<1078, 256, 0, stream>>>(dc1_w, dc2_w, dc3_w, off1_w, off2_w, off3_w,
                                   wp1h, wp1l, wp2h, wp2l, wp3h, wp3l,
                                   w0t1, w0t2, w0t3);

  // stage 1
  k_conv1<<<BATCH, 256, 0, stream>>>(x, conv1_w, conv1_b, h1, sum1, sq1);
  k_bnfin<<<1, 128, 0, stream>>>(sum1, sq1, bn1_g, bn1_b, sc1, sh1, 32, 1.0f / 524288.0f);
  k_dconv<32, 16, 16, 2, 8, 8, 64><<<BATCH, 256, 0, stream>>>(
      h1, sc1, sh1, w0t1, off1_b, wp1h, wp1l, h2);

  // stage 2
  k_stats<64, 256><<<512, 256, 0, stream>>>(h2, sum2, sq2);
  k_bnfin<<<1, 128, 0, stream>>>(sum2, sq2, bn2_g, bn2_b, sc2, sh2, 64, 1.0f / 131072.0f);
  k_dconv<64, 8, 8, 1, 8, 8, 128><<<BATCH, 256, 0, stream>>>(
      h2, sc2, sh2, w0t2, off2_b, wp2h, wp2l, h3);

  // stage 3
  k_stats<128, 256><<<512, 256, 0, stream>>>(h3, sum3, sq3);
  k_bnfin<<<1, 128, 0, stream>>>(sum3, sq3, bn3_g, bn3_b, sc3, sh3, 128, 1.0f / 131072.0f);
  k_dconv<128, 8, 8, 2, 4, 4, 128><<<BATCH, 256, 0, stream>>>(
      h3, sc3, sh3, w0t3, off3_b, wp3h, wp3l, h4);

  // stage 4
  k_stats<128, 128><<<256, 256, 0, stream>>>(h4, sum4, sq4);
  k_bnfin<<<1, 128, 0, stream>>>(sum4, sq4, bn4_g, bn4_b, sc4, sh4, 128, 1.0f / 32768.0f);
  k_poolfc<<<BATCH, 128, 0, stream>>>(h4, sc4, sh4, fc_w, fc_b, out);
}

// Round 7
// 523.957 us; speedup vs baseline: 29.8114x; 1.4161x over previous
//
#include <hip/hip_runtime.h>

#define BATCH 2048

typedef __attribute__((ext_vector_type(8))) short bf16x8;
typedef __attribute__((ext_vector_type(4))) float f32x4;

__device__ inline float bf2f(unsigned short u) {
  union { unsigned int i; float f; } v;
  v.i = ((unsigned int)u) << 16;
  return v.f;
}
__device__ inline unsigned short f2bf(float f) {
  union { float f; unsigned int i; } v;
  v.f = f;
  unsigned int r = v.i + 0x7FFFu + ((v.i >> 16) & 1u);
  return (unsigned short)(r >> 16);
}

// -------------------------------------------------- conv1 + bias + relu + bn1 stats
// out layout: [b][pos(256)][co(32)]; stats -> bucketed [8][2][128]
__global__ __launch_bounds__(256) void k_conv1(
    const float* __restrict__ x, const float* __restrict__ w,
    const float* __restrict__ bias, float* __restrict__ out,
    float* __restrict__ stat) {
  __shared__ float xs[324];
  __shared__ float wsm[288];
  __shared__ float red[512];
  int b = blockIdx.x, t = threadIdx.x;
  const float* xb = x + (size_t)b * 324;
  for (int i = t; i < 324; i += 256) xs[i] = xb[i];
  for (int i = t; i < 288; i += 256) wsm[i] = w[i];
  __syncthreads();
  int co = t & 31, pp = t >> 5;
  float wv[9];
#pragma unroll
  for (int k = 0; k < 9; k++) wv[k] = wsm[co * 9 + k];
  float bb = bias[co];
  float sp = 0.0f, qp = 0.0f;
  float* ob = out + (size_t)b * 8192;
  for (int i = 0; i < 32; i++) {
    int pos = (i << 3) + pp;
    int ho = pos >> 4, wo = pos & 15;
    float a = bb;
#pragma unroll
    for (int ki = 0; ki < 3; ki++)
#pragma unroll
      for (int kj = 0; kj < 3; kj++)
        a = fmaf(xs[(ho + ki) * 18 + wo + kj], wv[ki * 3 + kj], a);
    a = fmaxf(a, 0.0f);
    ob[pos * 32 + co] = a;
    sp += a;
    qp = fmaf(a, a, qp);
  }
  red[t] = sp;
  red[256 + t] = qp;
  __syncthreads();
  if (t < 32) {
    float S = 0.0f, Q = 0.0f;
#pragma unroll
    for (int r = 0; r < 8; r++) {
      S += red[r * 32 + t];
      Q += red[256 + r * 32 + t];
    }
    int bk = (b & 7) * 256;
    atomicAdd(stat + bk + t, S);
    atomicAdd(stat + bk + 128 + t, Q);
  }
}

// ------------------------------------------------------------ bn finalize (bucketed)
__global__ void k_bnfin(const float* __restrict__ st,
                        const float* __restrict__ g, const float* __restrict__ beta,
                        float* __restrict__ scale, float* __restrict__ shift,
                        int C, float invN) {
  int c = threadIdx.x;
  if (c < C) {
    float m = 0.0f, v = 0.0f;
#pragma unroll
    for (int j = 0; j < 8; j++) {
      m += st[j * 256 + c];
      v += st[j * 256 + 128 + c];
    }
    m *= invN;
    v = v * invN - m * m;
    float sc = rsqrtf(v + 1e-5f) * g[c];
    scale[c] = sc;
    shift[c] = beta[c] - m * sc;
  }
}

// ------------------------------------------------------------ weight prep
// dc weights -> split-bf16 MFMA B-fragment packs (hi & lo): [tap][ks][ct][lane][8]
//   ci = ks*32 + (lane>>4)*8 + j ; co = ct*16 + (lane&15)
// off weights -> fp32 [k][ci][18]
__global__ __launch_bounds__(256) void k_prep(
    const float* __restrict__ dc1, const float* __restrict__ dc2,
    const float* __restrict__ dc3, const float* __restrict__ ow1,
    const float* __restrict__ ow2, const float* __restrict__ ow3,
    unsigned short* __restrict__ wp1h, unsigned short* __restrict__ wp1l,
    unsigned short* __restrict__ wp2h, unsigned short* __restrict__ wp2l,
    unsigned short* __restrict__ wp3h, unsigned short* __restrict__ wp3l,
    float* __restrict__ w0t1, float* __restrict__ w0t2, float* __restrict__ w0t3) {
  int idx = blockIdx.x * 256 + threadIdx.x;
  if (idx < 239616) {
    int e = idx;
    const float* src; unsigned short *dh, *dl; int CIN, NCT, KS;
    if (e < 18432)      { src = dc1; dh = wp1h; dl = wp1l; CIN = 32;  NCT = 4; KS = 1; }
    else if (e < 92160) { e -= 18432; src = dc2; dh = wp2h; dl = wp2l; CIN = 64;  NCT = 8; KS = 2; }
    else                { e -= 92160; src = dc3; dh = wp3h; dl = wp3l; CIN = 128; NCT = 8; KS = 4; }
    int j = e & 7, lane = (e >> 3) & 63;
    int rest = e >> 9;
    int ct = rest % NCT; rest /= NCT;
    int ks = rest % KS;
    int tap = rest / KS;
    int ci = ks * 32 + ((lane >> 4) << 3) + j;
    int co = ct * 16 + (lane & 15);
    float wv = src[((size_t)co * CIN + ci) * 9 + tap];
    unsigned short h = f2bf(wv);
    dh[e] = h;
    dl[e] = f2bf(wv - bf2f(h));
  } else if (idx < 275904) {
    int e = idx - 239616;
    const float* in; float* out; int CI;
    if (e < 5184)       { in = ow1; out = w0t1; CI = 32; }
    else if (e < 15552) { e -= 5184;  in = ow2; out = w0t2; CI = 64; }
    else                { e -= 15552; in = ow3; out = w0t3; CI = 128; }
    int co = e % 18;
    int r = e / 18;
    int ci = r % CI;
    int k = r / CI;
    out[e] = in[((size_t)co * CI + ci) * 9 + k];
  }
}

// ------------------------------------------------------------ bilinear helper
template <int H, int W>
__device__ inline void bilin_setup(float py, float px, float& w00, float& w01,
                                   float& w10, float& w11, int& p00, int& p01,
                                   int& p10, int& p11, int CP) {
  float y0f = floorf(py), x0f = floorf(px);
  float wy = py - y0f, wx = px - x0f;
  int y0 = (int)y0f, x0 = (int)x0f, y1 = y0 + 1, x1 = x0 + 1;
  w00 = (1.0f - wy) * (1.0f - wx);
  w01 = (1.0f - wy) * wx;
  w10 = wy * (1.0f - wx);
  w11 = wy * wx;
  bool vy0 = (unsigned)y0 < (unsigned)H, vy1 = (unsigned)y1 < (unsigned)H;
  bool vx0 = (unsigned)x0 < (unsigned)W, vx1 = (unsigned)x1 < (unsigned)W;
  w00 = (vy0 && vx0) ? w00 : 0.0f;
  w01 = (vy0 && vx1) ? w01 : 0.0f;
  w10 = (vy1 && vx0) ? w10 : 0.0f;
  w11 = (vy1 && vx1) ? w11 : 0.0f;
  int yc0 = min(max(y0, 0), H - 1) * W, yc1 = min(max(y1, 0), H - 1) * W;
  int xc0 = min(max(x0, 0), W - 1),     xc1 = min(max(x1, 0), W - 1);
  p00 = (yc0 + xc0) * CP; p01 = (yc0 + xc1) * CP;
  p10 = (yc1 + xc0) * CP; p11 = (yc1 + xc1) * CP;
}

// ------------------------------------------------------------ fused offsetconv + deform conv, S=64
// Wave-independent main loop: each wave owns 16 output rows; NO barriers after phase 0.
// in/out layout [b][pos][ci]. Block = 1 image. Stats fused (bucketed).
template <int CIN, int H, int W, int STRIDE, int HO, int WO, int COUT, int MINB>
__global__ __launch_bounds__(256, MINB) void k_dconv12(
    const float* __restrict__ in, const float* __restrict__ scale,
    const float* __restrict__ shift, const float* __restrict__ w0t,
    const float* __restrict__ obias, const unsigned short* __restrict__ wph,
    const unsigned short* __restrict__ wpl, float* __restrict__ out,
    float* __restrict__ stat) {
  constexpr int S   = HO * WO;          // 64
  constexpr int HW  = H * W;
  constexpr int CP  = CIN + 4;          // fp32 tile row stride
  constexpr int AP  = CIN + 8;          // A-buffer row stride (ushorts)
  constexpr int CQ  = CIN / 4;          // ci per lane-quarter
  constexpr int NCT = COUT / 16;
  constexpr int KS  = CIN / 32;
  static_assert(S == 64 && CQ % 4 == 0, "geometry");

  __shared__ float tile[HW * CP];
  __shared__ float offs[18 * 64];
  __shared__ unsigned short abuf[4 * 2 * 16 * AP];

  int b = blockIdx.x, t = threadIdx.x;

  // ---- stage BN'd input as fp32 [pos][ci]; init offs with bias
  const float* inb = in + (size_t)b * CIN * HW;
  for (int i = t; i < HW * CIN / 4; i += 256) {
    int pos = i / (CIN / 4);
    int c4 = (i % (CIN / 4)) * 4;
    float4 v = *(const float4*)&inb[pos * CIN + c4];
    float4 sc = *(const float4*)&scale[c4];
    float4 sh = *(const float4*)&shift[c4];
    float4 o;
    o.x = fmaf(v.x, sc.x, sh.x);
    o.y = fmaf(v.y, sc.y, sh.y);
    o.z = fmaf(v.z, sc.z, sh.z);
    o.w = fmaf(v.w, sc.w, sh.w);
    *(float4*)&tile[pos * CP + c4] = o;
  }
  for (int o = t; o < 18 * 64; o += 256) offs[o] = obias[o >> 6];
  __syncthreads();

  // ---- phase 0: offset conv; rep = wave (uniform) -> scalar weight loads
  {
    int s0 = t & 63;
    int rep = __builtin_amdgcn_readfirstlane(t >> 6);
    int ho = s0 / WO, wo = s0 % WO;
    int ci0 = rep * CQ;
    float a0[18];
#pragma unroll
    for (int c = 0; c < 18; c++) a0[c] = 0.0f;
    for (int k = 0; k < 9; k++) {
      int y = ho * STRIDE - 1 + k / 3;
      int x = wo * STRIDE - 1 + k % 3;
      bool valid = ((unsigned)y < (unsigned)H) && ((unsigned)x < (unsigned)W);
      int pos = valid ? y * W + x : 0;
#pragma unroll
      for (int g = 0; g < CQ / 4; g++) {
        int ci = ci0 + g * 4;
        float4 f = *(const float4*)&tile[pos * CP + ci];
        float tv[4] = {f.x, f.y, f.z, f.w};
        if (!valid) { tv[0] = tv[1] = tv[2] = tv[3] = 0.0f; }
        int base = __builtin_amdgcn_readfirstlane((k * CIN + ci) * 18);
        const float* wp = w0t + base;
#pragma unroll
        for (int j = 0; j < 4; j++)
#pragma unroll
          for (int c = 0; c < 18; c++)
            a0[c] = fmaf(tv[j], wp[j * 18 + c], a0[c]);
      }
    }
#pragma unroll
    for (int c = 0; c < 18; c++) atomicAdd(&offs[c * 64 + s0], a0[c]);
  }
  __syncthreads();
  // ======== from here on: NO block barriers — each wave fully independent ========

  int lane = t & 63, w = t >> 6;
  int srow = lane & 15, q = lane >> 4;
  int s = w * 16 + srow;
  int ho_a = s / WO, wo_a = s % WO;
  int ciA = q * CQ;
  unsigned short* abufW = abuf + w * (2 * 16 * AP);
  f32x4 acc[NCT];
#pragma unroll
  for (int ct = 0; ct < NCT; ct++) acc[ct] = (f32x4){0.f, 0.f, 0.f, 0.f};

  for (int k = 0; k < 9; k++) {
    float dy = offs[(2 * k) * 64 + s];
    float dx = offs[(2 * k + 1) * 64 + s];
    float py = (float)(ho_a * STRIDE - 1 + k / 3) + dy;
    float px = (float)(wo_a * STRIDE - 1 + k % 3) + dx;
    float w00, w01, w10, w11;
    int p00, p01, p10, p11;
    bilin_setup<H, W>(py, px, w00, w01, w10, w11, p00, p01, p10, p11, CP);
#pragma unroll
    for (int g = 0; g < CQ / 4; g++) {
      int ci = ciA + g * 4;
      float4 f00 = *(const float4*)&tile[p00 + ci];
      float4 f01 = *(const float4*)&tile[p01 + ci];
      float4 f10 = *(const float4*)&tile[p10 + ci];
      float4 f11 = *(const float4*)&tile[p11 + ci];
      float v0 = w00 * f00.x + w01 * f01.x + w10 * f10.x + w11 * f11.x;
      float v1 = w00 * f00.y + w01 * f01.y + w10 * f10.y + w11 * f11.y;
      float v2 = w00 * f00.z + w01 * f01.z + w10 * f10.z + w11 * f11.z;
      float v3 = w00 * f00.w + w01 * f01.w + w10 * f10.w + w11 * f11.w;
      ushort4 h, l;
      h.x = f2bf(v0); l.x = f2bf(v0 - bf2f(h.x));
      h.y = f2bf(v1); l.y = f2bf(v1 - bf2f(h.y));
      h.z = f2bf(v2); l.z = f2bf(v2 - bf2f(h.z));
      h.w = f2bf(v3); l.w = f2bf(v3 - bf2f(h.w));
      *(ushort4*)&abufW[srow * AP + ci] = h;
      *(ushort4*)&abufW[16 * AP + srow * AP + ci] = l;
    }
    // MFMA (wave reads only its own abuf slice; lgkmcnt ordering, no barrier)
    const unsigned short* wkh = wph + (size_t)k * KS * NCT * 512;
    const unsigned short* wkl = wpl + (size_t)k * KS * NCT * 512;
#pragma unroll
    for (int ks = 0; ks < KS; ks++) {
      bf16x8 ah = *(const bf16x8*)&abufW[srow * AP + ks * 32 + q * 8];
      bf16x8 al = *(const bf16x8*)&abufW[16 * AP + srow * AP + ks * 32 + q * 8];
#pragma unroll
      for (int ct = 0; ct < NCT; ct++) {
        const bf16x8 bh = *(const bf16x8*)&wkh[((ks * NCT + ct) * 64 + lane) * 8];
        const bf16x8 bl = *(const bf16x8*)&wkl[((ks * NCT + ct) * 64 + lane) * 8];
        acc[ct] = __builtin_amdgcn_mfma_f32_16x16x32_bf16(ah, bh, acc[ct], 0, 0, 0);
        acc[ct] = __builtin_amdgcn_mfma_f32_16x16x32_bf16(al, bh, acc[ct], 0, 0, 0);
        acc[ct] = __builtin_amdgcn_mfma_f32_16x16x32_bf16(ah, bl, acc[ct], 0, 0, 0);
      }
    }
  }

  // ---- epilogue: relu + store + fused BN stats
  float* ob = out + (size_t)b * S * COUT;
  int bk = (b & 7) * 256;
#pragma unroll
  for (int ct = 0; ct < NCT; ct++) {
    int co = ct * 16 + srow;
    int sr = w * 16 + (q << 2);
    float sp = 0.0f, qp = 0.0f;
#pragma unroll
    for (int r = 0; r < 4; r++) {
      float v = fmaxf(acc[ct][r], 0.0f);
      ob[(sr + r) * COUT + co] = v;
      sp += v;
      qp = fmaf(v, v, qp);
    }
    sp += __shfl_xor(sp, 16, 64); sp += __shfl_xor(sp, 32, 64);
    qp += __shfl_xor(qp, 16, 64); qp += __shfl_xor(qp, 32, 64);
    if (q == 0) {
      atomicAdd(stat + bk + co, sp);
      atomicAdd(stat + bk + 128 + co, qp);
    }
  }
}

// ------------------------------------------------------------ stage-3 deform conv, S=16
// Cooperative phase A + ping-pong abuf: exactly 1 barrier per tap.
__global__ __launch_bounds__(256, 3) void k_dconv3(
    const float* __restrict__ in, const float* __restrict__ scale,
    const float* __restrict__ shift, const float* __restrict__ w0t,
    const float* __restrict__ obias, const unsigned short* __restrict__ wph,
    const unsigned short* __restrict__ wpl, float* __restrict__ out,
    float* __restrict__ stat) {
  constexpr int CIN = 128, H = 8, W = 8, STRIDE = 2, HO = 4, WO = 4, COUT = 128;
  constexpr int S = 16, HW = 64, CP = CIN + 4, AP = CIN + 8;
  constexpr int NCT = 8, KS = 4;

  __shared__ float tile[HW * CP];
  __shared__ float offs[18 * 16];
  __shared__ unsigned short abuf[2][2 * 16 * AP];

  int b = blockIdx.x, t = threadIdx.x;

  const float* inb = in + (size_t)b * CIN * HW;
  for (int i = t; i < HW * CIN / 4; i += 256) {
    int pos = i / (CIN / 4);
    int c4 = (i % (CIN / 4)) * 4;
    float4 v = *(const float4*)&inb[pos * CIN + c4];
    float4 sc = *(const float4*)&scale[c4];
    float4 sh = *(const float4*)&shift[c4];
    float4 o;
    o.x = fmaf(v.x, sc.x, sh.x);
    o.y = fmaf(v.y, sc.y, sh.y);
    o.z = fmaf(v.z, sc.z, sh.z);
    o.w = fmaf(v.w, sc.w, sh.w);
    *(float4*)&tile[pos * CP + c4] = o;
  }
  // FIX (R6 bug): 288 > 256 threads -> strided loop, not `if (t < 288)`
  for (int o = t; o < 288; o += 256) offs[o] = obias[o >> 4];
  __syncthreads();

  int lane = t & 63, w = t >> 6;
  int srow = lane & 15, q = lane >> 4;

  // ---- phase 0: offset conv, 16 reps of 8 ci; shuffle(4)+LDS-atomic(4) reduce
  {
    int s0 = t & 15;
    int rep = t >> 4;
    int ho = s0 >> 2, wo = s0 & 3;
    int ci0 = rep * 8;
    float a0[18];
#pragma unroll
    for (int c = 0; c < 18; c++) a0[c] = 0.0f;
    for (int k = 0; k < 9; k++) {
      int y = ho * STRIDE - 1 + k / 3;
      int x = wo * STRIDE - 1 + k % 3;
      bool valid = ((unsigned)y < (unsigned)H) && ((unsigned)x < (unsigned)W);
      int pos = valid ? y * W + x : 0;
#pragma unroll
      for (int g = 0; g < 2; g++) {
        int ci = ci0 + g * 4;
        float4 f = *(const float4*)&tile[pos * CP + ci];
        float tv[4] = {f.x, f.y, f.z, f.w};
        if (!valid) { tv[0] = tv[1] = tv[2] = tv[3] = 0.0f; }
        const float* wp = w0t + (k * CIN + ci) * 18;
#pragma unroll
        for (int j = 0; j < 4; j++)
#pragma unroll
          for (int c = 0; c < 18; c++)
            a0[c] = fmaf(tv[j], wp[j * 18 + c], a0[c]);
      }
    }
#pragma unroll
    for (int c = 0; c < 18; c++) {
      a0[c] += __shfl_xor(a0[c], 16, 64);
      a0[c] += __shfl_xor(a0[c], 32, 64);
    }
    if (q == 0) {
#pragma unroll
      for (int c = 0; c < 18; c++) atomicAdd(&offs[c * 16 + srow], a0[c]);
    }
  }
  __syncthreads();

  // ---- main loop: ping-pong A buffer, 1 barrier per tap
  int ct0 = w * 2;
  f32x4 acc[2];
  acc[0] = (f32x4){0.f, 0.f, 0.f, 0.f};
  acc[1] = (f32x4){0.f, 0.f, 0.f, 0.f};

  int sA = t & 15;
  int repA = t >> 4;
  int hoA = sA >> 2, woA = sA & 3;
  int ciA = repA * 8;
  int p = 0;

  for (int k = 0; k < 9; k++) {
    {
      float dy = offs[(2 * k) * 16 + sA];
      float dx = offs[(2 * k + 1) * 16 + sA];
      float py = (float)(hoA * STRIDE - 1 + k / 3) + dy;
      float px = (float)(woA * STRIDE - 1 + k % 3) + dx;
      float w00, w01, w10, w11;
      int p00, p01, p10, p11;
      bilin_setup<H, W>(py, px, w00, w01, w10, w11, p00, p01, p10, p11, CP);
      unsigned short* ab = abuf[p];
#pragma unroll
      for (int g = 0; g < 2; g++) {
        int ci = ciA + g * 4;
        float4 f00 = *(const float4*)&tile[p00 + ci];
        float4 f01 = *(const float4*)&tile[p01 + ci];
        float4 f10 = *(const float4*)&tile[p10 + ci];
        float4 f11 = *(const float4*)&tile[p11 + ci];
        float v0 = w00 * f00.x + w01 * f01.x + w10 * f10.x + w11 * f11.x;
        float v1 = w00 * f00.y + w01 * f01.y + w10 * f10.y + w11 * f11.y;
        float v2 = w00 * f00.z + w01 * f01.z + w10 * f10.z + w11 * f11.z;
        float v3 = w00 * f00.w + w01 * f01.w + w10 * f10.w + w11 * f11.w;
        ushort4 h, l;
        h.x = f2bf(v0); l.x = f2bf(v0 - bf2f(h.x));
        h.y = f2bf(v1); l.y = f2bf(v1 - bf2f(h.y));
        h.z = f2bf(v2); l.z = f2bf(v2 - bf2f(h.z));
        h.w = f2bf(v3); l.w = f2bf(v3 - bf2f(h.w));
        *(ushort4*)&ab[sA * AP + ci] = h;
        *(ushort4*)&ab[16 * AP + sA * AP + ci] = l;
      }
    }
    __syncthreads();
    const unsigned short* wkh = wph + (size_t)k * KS * NCT * 512;
    const unsigned short* wkl = wpl + (size_t)k * KS * NCT * 512;
    const unsigned short* ab = abuf[p];
#pragma unroll
    for (int ks = 0; ks < KS; ks++) {
      bf16x8 ah = *(const bf16x8*)&ab[srow * AP + ks * 32 + q * 8];
      bf16x8 al = *(const bf16x8*)&ab[16 * AP + srow * AP + ks * 32 + q * 8];
#pragma unroll
      for (int ctl = 0; ctl < 2; ctl++) {
        int ct = ct0 + ctl;
        const bf16x8 bh = *(const bf16x8*)&wkh[((ks * NCT + ct) * 64 + lane) * 8];
        const bf16x8 bl = *(const bf16x8*)&wkl[((ks * NCT + ct) * 64 + lane) * 8];
        acc[ctl] = __builtin_amdgcn_mfma_f32_16x16x32_bf16(ah, bh, acc[ctl], 0, 0, 0);
        acc[ctl] = __builtin_amdgcn_mfma_f32_16x16x32_bf16(al, bh, acc[ctl], 0, 0, 0);
        acc[ctl] = __builtin_amdgcn_mfma_f32_16x16x32_bf16(ah, bl, acc[ctl], 0, 0, 0);
      }
    }
    p ^= 1;
  }

  // ---- epilogue: relu + store + fused BN stats
  float* ob = out + (size_t)b * S * COUT;
  int bk = (b & 7) * 256;
#pragma unroll
  for (int ctl = 0; ctl < 2; ctl++) {
    int co = (ct0 + ctl) * 16 + srow;
    int sr = q << 2;
    float sp = 0.0f, qp = 0.0f;
#pragma unroll
    for (int r = 0; r < 4; r++) {
      float v = fmaxf(acc[ctl][r], 0.0f);
      ob[(sr + r) * COUT + co] = v;
      sp += v;
      qp = fmaf(v, v, qp);
    }
    sp += __shfl_xor(sp, 16, 64); sp += __shfl_xor(sp, 32, 64);
    qp += __shfl_xor(qp, 16, 64); qp += __shfl_xor(qp, 32, 64);
    if (q == 0) {
      atomicAdd(stat + bk + co, sp);
      atomicAdd(stat + bk + 128 + co, qp);
    }
  }
}

// ------------------------------------------------------------ pool + fc  (h4: [b][s][128])
__global__ __launch_bounds__(128) void k_poolfc(
    const float* __restrict__ h4, const float* __restrict__ scale,
    const float* __restrict__ shift, const float* __restrict__ fcw,
    const float* __restrict__ fcb, float* __restrict__ out) {
  __shared__ float pooled[128];
  int b = blockIdx.x;
  int c = threadIdx.x;
  const float* hb = h4 + (size_t)b * 2048;
  float sm = 0.0f;
#pragma unroll
  for (int s = 0; s < 16; s++) sm += hb[s * 128 + c];
  pooled[c] = fmaf(sm * (1.0f / 16.0f), scale[c], shift[c]);
  __syncthreads();
  if (c < 10) {
    float acc = fcb[c];
#pragma unroll
    for (int i = 0; i < 128; i++) acc = fmaf(pooled[i], fcw[c * 128 + i], acc);
    out[(size_t)b * 10 + c] = acc;
  }
}

// ---------------------------------------------------------------- launch
extern "C" void kernel_launch(void* const* d_in, const int* in_sizes, int n_in,
                              void* d_out, int out_size, void* d_ws, size_t ws_size,
                              hipStream_t stream) {
  const float* x       = (const float*)d_in[0];
  const float* conv1_w = (const float*)d_in[1];
  const float* conv1_b = (const float*)d_in[2];
  const float* bn1_g   = (const float*)d_in[3];
  const float* bn1_b   = (const float*)d_in[4];
  const float* off1_w  = (const float*)d_in[5];
  const float* off1_b  = (const float*)d_in[6];
  const float* dc1_w   = (const float*)d_in[7];
  const float* bn2_g   = (const float*)d_in[8];
  const float* bn2_b   = (const float*)d_in[9];
  const float* off2_w  = (const float*)d_in[10];
  const float* off2_b  = (const float*)d_in[11];
  const float* dc2_w   = (const float*)d_in[12];
  const float* bn3_g   = (const float*)d_in[13];
  const float* bn3_b   = (const float*)d_in[14];
  const float* off3_w  = (const float*)d_in[15];
  const float* off3_b  = (const float*)d_in[16];
  const float* dc3_w   = (const float*)d_in[17];
  const float* bn4_g   = (const float*)d_in[18];
  const float* bn4_b   = (const float*)d_in[19];
  const float* fc_w    = (const float*)d_in[20];
  const float* fc_b    = (const float*)d_in[21];
  float* out = (float*)d_out;

  float* wsf = (float*)d_ws;
  // region A: h1 [2048][256][32] / h3 [2048][64][128] alias — 16777216 floats
  float* h1 = wsf;
  float* h3 = wsf;
  // region B: h2 [2048][64][64] / h4 [2048][16][128] alias — 8388608 floats
  float* h2 = wsf + 16777216;
  float* h4 = wsf + 16777216;
  float* wbase = wsf + 25165824;
  unsigned short* wp1h = (unsigned short*)wbase;   // hi/lo dc packs
  unsigned short* wp1l = wp1h + 18432;
  unsigned short* wp2h = wp1l + 18432;
  unsigned short* wp2l = wp2h + 73728;
  unsigned short* wp3h = wp2l + 73728;
  unsigned short* wp3l = wp3h + 147456;            // total 479232 ushorts = 239616 floats
  float* w0t1 = wbase + 239616;                    // 5184 floats
  float* w0t2 = w0t1 + 5184;                       // 10368
  float* w0t3 = w0t2 + 10368;                      // 20736
  // stats: per stage bucketed sums [8][2][128] (2048 floats) x 4 stages, then sc/sh
  float* stat0 = wbase + 275904;
  float* stat1 = stat0 + 2048;
  float* stat2 = stat1 + 2048;
  float* stat3 = stat2 + 2048;
  float* scsh  = stat0 + 8192;
  float* sc1 = scsh + 0,    *sh1 = scsh + 128;
  float* sc2 = scsh + 256,  *sh2 = scsh + 384;
  float* sc3 = scsh + 512,  *sh3 = scsh + 640;
  float* sc4 = scsh + 768,  *sh4 = scsh + 896;

  hipMemsetAsync(stat0, 0, 8192 * sizeof(float), stream);
  k_prep<<<1078, 256, 0, stream>>>(dc1_w, dc2_w, dc3_w, off1_w, off2_w, off3_w,
                                   wp1h, wp1l, wp2h, wp2l, wp3h, wp3l,
                                   w0t1, w0t2, w0t3);

  // stage 1
  k_conv1<<<BATCH, 256, 0, stream>>>(x, conv1_w, conv1_b, h1, stat0);
  k_bnfin<<<1, 128, 0, stream>>>(stat0, bn1_g, bn1_b, sc1, sh1, 32, 1.0f / 524288.0f);
  k_dconv12<32, 16, 16, 2, 8, 8, 64, 3><<<BATCH, 256, 0, stream>>>(
      h1, sc1, sh1, w0t1, off1_b, wp1h, wp1l, h2, stat1);

  // stage 2
  k_bnfin<<<1, 128, 0, stream>>>(stat1, bn2_g, bn2_b, sc2, sh2, 64, 1.0f / 131072.0f);
  k_dconv12<64, 8, 8, 1, 8, 8, 128, 4><<<BATCH, 256, 0, stream>>>(
      h2, sc2, sh2, w0t2, off2_b, wp2h, wp2l, h3, stat2);

  // stage 3
  k_bnfin<<<1, 128, 0, stream>>>(stat2, bn3_g, bn3_b, sc3, sh3, 128, 1.0f / 131072.0f);
  k_dconv3<<<BATCH, 256, 0, stream>>>(
      h3, sc3, sh3, w0t3, off3_b, wp3h, wp3l, h4, stat3);

  // stage 4
  k_bnfin<<<1, 128, 0, stream>>>(stat3, bn4_g, bn4_b, sc4, sh4, 128, 1.0f / 32768.0f);
  k_poolfc<<<BATCH, 128, 0, stream>>>(h4, sc4, sh4, fc_w, fc_b, out);
}

// Round 8
// 470.916 us; speedup vs baseline: 33.1691x; 1.1126x over previous
//
#include <hip/hip_runtime.h>

#define BATCH 2048

typedef _Float16 f16;
typedef __attribute__((ext_vector_type(8))) f16 f16x8;
typedef __attribute__((ext_vector_type(4))) float f32x4;

__device__ inline unsigned short f2h(float f) {
  union { f16 h; unsigned short u; } v;
  v.h = (f16)f;
  return v.u;
}
__device__ inline float h2f(unsigned short u) {
  union { f16 h; unsigned short u; } v;
  v.u = u;
  return (float)v.h;
}

// -------------------------------------------------- conv1 + bias + relu + bn1 stats
// out layout: [b][pos(256)][co(32)]; stats -> bucketed [8][2][128]
__global__ __launch_bounds__(256) void k_conv1(
    const float* __restrict__ x, const float* __restrict__ w,
    const float* __restrict__ bias, float* __restrict__ out,
    float* __restrict__ stat) {
  __shared__ float xs[324];
  __shared__ float wsm[288];
  __shared__ float red[512];
  int b = blockIdx.x, t = threadIdx.x;
  const float* xb = x + (size_t)b * 324;
  for (int i = t; i < 324; i += 256) xs[i] = xb[i];
  for (int i = t; i < 288; i += 256) wsm[i] = w[i];
  __syncthreads();
  int co = t & 31, pp = t >> 5;
  float wv[9];
#pragma unroll
  for (int k = 0; k < 9; k++) wv[k] = wsm[co * 9 + k];
  float bb = bias[co];
  float sp = 0.0f, qp = 0.0f;
  float* ob = out + (size_t)b * 8192;
  for (int i = 0; i < 32; i++) {
    int pos = (i << 3) + pp;
    int ho = pos >> 4, wo = pos & 15;
    float a = bb;
#pragma unroll
    for (int ki = 0; ki < 3; ki++)
#pragma unroll
      for (int kj = 0; kj < 3; kj++)
        a = fmaf(xs[(ho + ki) * 18 + wo + kj], wv[ki * 3 + kj], a);
    a = fmaxf(a, 0.0f);
    ob[pos * 32 + co] = a;
    sp += a;
    qp = fmaf(a, a, qp);
  }
  red[t] = sp;
  red[256 + t] = qp;
  __syncthreads();
  if (t < 32) {
    float S = 0.0f, Q = 0.0f;
#pragma unroll
    for (int r = 0; r < 8; r++) {
      S += red[r * 32 + t];
      Q += red[256 + r * 32 + t];
    }
    int bk = (b & 7) * 256;
    atomicAdd(stat + bk + t, S);
    atomicAdd(stat + bk + 128 + t, Q);
  }
}

// ------------------------------------------------------------ bn finalize (bucketed)
__global__ void k_bnfin(const float* __restrict__ st,
                        const float* __restrict__ g, const float* __restrict__ beta,
                        float* __restrict__ scale, float* __restrict__ shift,
                        int C, float invN) {
  int c = threadIdx.x;
  if (c < C) {
    float m = 0.0f, v = 0.0f;
#pragma unroll
    for (int j = 0; j < 8; j++) {
      m += st[j * 256 + c];
      v += st[j * 256 + 128 + c];
    }
    m *= invN;
    v = v * invN - m * m;
    float sc = rsqrtf(v + 1e-5f) * g[c];
    scale[c] = sc;
    shift[c] = beta[c] - m * sc;
  }
}

// ------------------------------------------------------------ weight prep
// dc weights -> single fp16 MFMA B-fragment pack: [tap][ks][ct][lane][8]
//   ci = ks*32 + (lane>>4)*8 + j ; co = ct*16 + (lane&15)
// off weights -> fp32 [k][ci][18]
__global__ __launch_bounds__(256) void k_prep(
    const float* __restrict__ dc1, const float* __restrict__ dc2,
    const float* __restrict__ dc3, const float* __restrict__ ow1,
    const float* __restrict__ ow2, const float* __restrict__ ow3,
    unsigned short* __restrict__ wp1, unsigned short* __restrict__ wp2,
    unsigned short* __restrict__ wp3, float* __restrict__ w0t1,
    float* __restrict__ w0t2, float* __restrict__ w0t3) {
  int idx = blockIdx.x * 256 + threadIdx.x;
  if (idx < 239616) {
    int e = idx;
    const float* src; unsigned short* dst; int CIN, NCT, KS;
    if (e < 18432)      { src = dc1; dst = wp1; CIN = 32;  NCT = 4; KS = 1; }
    else if (e < 92160) { e -= 18432; src = dc2; dst = wp2; CIN = 64;  NCT = 8; KS = 2; }
    else                { e -= 92160; src = dc3; dst = wp3; CIN = 128; NCT = 8; KS = 4; }
    int j = e & 7, lane = (e >> 3) & 63;
    int rest = e >> 9;
    int ct = rest % NCT; rest /= NCT;
    int ks = rest % KS;
    int tap = rest / KS;
    int ci = ks * 32 + ((lane >> 4) << 3) + j;
    int co = ct * 16 + (lane & 15);
    dst[e] = f2h(src[((size_t)co * CIN + ci) * 9 + tap]);
  } else if (idx < 275904) {
    int e = idx - 239616;
    const float* in; float* out; int CI;
    if (e < 5184)       { in = ow1; out = w0t1; CI = 32; }
    else if (e < 15552) { e -= 5184;  in = ow2; out = w0t2; CI = 64; }
    else                { e -= 15552; in = ow3; out = w0t3; CI = 128; }
    int co = e % 18;
    int r = e / 18;
    int ci = r % CI;
    int k = r / CI;
    out[e] = in[((size_t)co * CI + ci) * 9 + k];
  }
}

// ------------------------------------------------------------ bilinear helper
template <int H, int W>
__device__ inline void bilin_setup(float py, float px, float& w00, float& w01,
                                   float& w10, float& w11, int& p00, int& p01,
                                   int& p10, int& p11, int CP) {
  float y0f = floorf(py), x0f = floorf(px);
  float wy = py - y0f, wx = px - x0f;
  int y0 = (int)y0f, x0 = (int)x0f, y1 = y0 + 1, x1 = x0 + 1;
  w00 = (1.0f - wy) * (1.0f - wx);
  w01 = (1.0f - wy) * wx;
  w10 = wy * (1.0f - wx);
  w11 = wy * wx;
  bool vy0 = (unsigned)y0 < (unsigned)H, vy1 = (unsigned)y1 < (unsigned)H;
  bool vx0 = (unsigned)x0 < (unsigned)W, vx1 = (unsigned)x1 < (unsigned)W;
  w00 = (vy0 && vx0) ? w00 : 0.0f;
  w01 = (vy0 && vx1) ? w01 : 0.0f;
  w10 = (vy1 && vx0) ? w10 : 0.0f;
  w11 = (vy1 && vx1) ? w11 : 0.0f;
  int yc0 = min(max(y0, 0), H - 1) * W, yc1 = min(max(y1, 0), H - 1) * W;
  int xc0 = min(max(x0, 0), W - 1),     xc1 = min(max(x1, 0), W - 1);
  p00 = (yc0 + xc0) * CP; p01 = (yc0 + xc1) * CP;
  p10 = (yc1 + xc0) * CP; p11 = (yc1 + xc1) * CP;
}

// ------------------------------------------------------------ fused offsetconv + deform conv, S=64
// ct-split cooperative GEMM: 4 waves share one A-buffer; each wave computes all 4
// row-tiles x (NCT/4) col-tiles -> each weight fragment read ONCE per block.
// fp16 split-A (hi+lo) x fp16 single-B, fp32 accum. 2 barriers per tap.
// in/out layout [b][pos][ci]. Block = 1 image. Stats fused (bucketed).
template <int CIN, int H, int W, int STRIDE, int HO, int WO, int COUT, int MINB>
__global__ __launch_bounds__(256, MINB) void k_dconv12(
    const float* __restrict__ in, const float* __restrict__ scale,
    const float* __restrict__ shift, const float* __restrict__ w0t,
    const float* __restrict__ obias, const unsigned short* __restrict__ wp,
    float* __restrict__ out, float* __restrict__ stat) {
  constexpr int S   = HO * WO;          // 64
  constexpr int HW  = H * W;
  constexpr int CP  = CIN + 4;          // fp32 tile row stride
  constexpr int AP  = CIN + 8;          // A-buffer row stride (ushorts)
  constexpr int CQ  = CIN / 4;          // ci per lane-quarter
  constexpr int NCT = COUT / 16;
  constexpr int KS  = CIN / 32;
  constexpr int CT_PER = NCT / 4;       // col tiles per wave (1 or 2)
  static_assert(S == 64 && CQ % 4 == 0 && CT_PER >= 1, "geometry");

  __shared__ float tile[HW * CP];
  __shared__ float offs[18 * 64];
  __shared__ unsigned short abuf[2 * S * AP];  // hi plane then lo plane

  int b = blockIdx.x, t = threadIdx.x;

  // ---- stage BN'd input as fp32 [pos][ci]; init offs with bias
  const float* inb = in + (size_t)b * CIN * HW;
  for (int i = t; i < HW * CIN / 4; i += 256) {
    int pos = i / (CIN / 4);
    int c4 = (i % (CIN / 4)) * 4;
    float4 v = *(const float4*)&inb[pos * CIN + c4];
    float4 sc = *(const float4*)&scale[c4];
    float4 sh = *(const float4*)&shift[c4];
    float4 o;
    o.x = fmaf(v.x, sc.x, sh.x);
    o.y = fmaf(v.y, sc.y, sh.y);
    o.z = fmaf(v.z, sc.z, sh.z);
    o.w = fmaf(v.w, sc.w, sh.w);
    *(float4*)&tile[pos * CP + c4] = o;
  }
  for (int o = t; o < 18 * 64; o += 256) offs[o] = obias[o >> 6];
  __syncthreads();

  // ---- phase 0: offset conv; rep = wave (uniform) -> scalar weight loads
  {
    int s0 = t & 63;
    int rep = __builtin_amdgcn_readfirstlane(t >> 6);
    int ho = s0 / WO, wo = s0 % WO;
    int ci0 = rep * CQ;
    float a0[18];
#pragma unroll
    for (int c = 0; c < 18; c++) a0[c] = 0.0f;
    for (int k = 0; k < 9; k++) {
      int y = ho * STRIDE - 1 + k / 3;
      int x = wo * STRIDE - 1 + k % 3;
      bool valid = ((unsigned)y < (unsigned)H) && ((unsigned)x < (unsigned)W);
      int pos = valid ? y * W + x : 0;
#pragma unroll
      for (int g = 0; g < CQ / 4; g++) {
        int ci = ci0 + g * 4;
        float4 f = *(const float4*)&tile[pos * CP + ci];
        float tv[4] = {f.x, f.y, f.z, f.w};
        if (!valid) { tv[0] = tv[1] = tv[2] = tv[3] = 0.0f; }
        int base = __builtin_amdgcn_readfirstlane((k * CIN + ci) * 18);
        const float* wpo = w0t + base;
#pragma unroll
        for (int j = 0; j < 4; j++)
#pragma unroll
          for (int c = 0; c < 18; c++)
            a0[c] = fmaf(tv[j], wpo[j * 18 + c], a0[c]);
      }
    }
#pragma unroll
    for (int c = 0; c < 18; c++) atomicAdd(&offs[c * 64 + s0], a0[c]);
  }
  __syncthreads();

  int lane = t & 63, w = t >> 6;
  int srow = lane & 15, q = lane >> 4;
  int s = w * 16 + srow;            // row this thread WRITES in phase A
  int ho_a = s / WO, wo_a = s % WO;
  int ciA = q * CQ;
  int ct0 = w * CT_PER;
  f32x4 acc[4][CT_PER];
#pragma unroll
  for (int rt = 0; rt < 4; rt++)
#pragma unroll
    for (int ct = 0; ct < CT_PER; ct++) acc[rt][ct] = (f32x4){0.f, 0.f, 0.f, 0.f};

  for (int k = 0; k < 9; k++) {
    if (k) __syncthreads();  // prev-tap MFMA reads done before overwrite
    // ---- phase A: bilinear -> split-fp16 A slice (this wave's 16 rows)
    {
      float dy = offs[(2 * k) * 64 + s];
      float dx = offs[(2 * k + 1) * 64 + s];
      float py = (float)(ho_a * STRIDE - 1 + k / 3) + dy;
      float px = (float)(wo_a * STRIDE - 1 + k % 3) + dx;
      float w00, w01, w10, w11;
      int p00, p01, p10, p11;
      bilin_setup<H, W>(py, px, w00, w01, w10, w11, p00, p01, p10, p11, CP);
#pragma unroll
      for (int g = 0; g < CQ / 4; g++) {
        int ci = ciA + g * 4;
        float4 f00 = *(const float4*)&tile[p00 + ci];
        float4 f01 = *(const float4*)&tile[p01 + ci];
        float4 f10 = *(const float4*)&tile[p10 + ci];
        float4 f11 = *(const float4*)&tile[p11 + ci];
        float v0 = w00 * f00.x + w01 * f01.x + w10 * f10.x + w11 * f11.x;
        float v1 = w00 * f00.y + w01 * f01.y + w10 * f10.y + w11 * f11.y;
        float v2 = w00 * f00.z + w01 * f01.z + w10 * f10.z + w11 * f11.z;
        float v3 = w00 * f00.w + w01 * f01.w + w10 * f10.w + w11 * f11.w;
        ushort4 h, l;
        h.x = f2h(v0); l.x = f2h(v0 - h2f(h.x));
        h.y = f2h(v1); l.y = f2h(v1 - h2f(h.y));
        h.z = f2h(v2); l.z = f2h(v2 - h2f(h.z));
        h.w = f2h(v3); l.w = f2h(v3 - h2f(h.w));
        *(ushort4*)&abuf[s * AP + ci] = h;
        *(ushort4*)&abuf[S * AP + s * AP + ci] = l;
      }
    }
    __syncthreads();  // A slice visible to all waves
    // ---- phase B: each wave MFMAs all 4 row-tiles x its CT_PER col-tiles
    const unsigned short* wk = wp + (size_t)k * KS * NCT * 512;
#pragma unroll
    for (int ks = 0; ks < KS; ks++) {
      f16x8 bv[CT_PER];
#pragma unroll
      for (int ctl = 0; ctl < CT_PER; ctl++)
        bv[ctl] = *(const f16x8*)&wk[((ks * NCT + ct0 + ctl) * 64 + lane) * 8];
#pragma unroll
      for (int rt = 0; rt < 4; rt++) {
        f16x8 ah = *(const f16x8*)&abuf[(rt * 16 + srow) * AP + ks * 32 + q * 8];
        f16x8 al = *(const f16x8*)&abuf[S * AP + (rt * 16 + srow) * AP + ks * 32 + q * 8];
#pragma unroll
        for (int ctl = 0; ctl < CT_PER; ctl++) {
          acc[rt][ctl] = __builtin_amdgcn_mfma_f32_16x16x32_f16(ah, bv[ctl], acc[rt][ctl], 0, 0, 0);
          acc[rt][ctl] = __builtin_amdgcn_mfma_f32_16x16x32_f16(al, bv[ctl], acc[rt][ctl], 0, 0, 0);
        }
      }
    }
  }

  // ---- epilogue: relu + store + fused BN stats
  float* ob = out + (size_t)b * S * COUT;
  int bk = (b & 7) * 256;
#pragma unroll
  for (int ctl = 0; ctl < CT_PER; ctl++) {
    int co = (ct0 + ctl) * 16 + srow;
    float sp = 0.0f, qp = 0.0f;
#pragma unroll
    for (int rt = 0; rt < 4; rt++) {
#pragma unroll
      for (int r = 0; r < 4; r++) {
        float v = fmaxf(acc[rt][ctl][r], 0.0f);
        ob[(rt * 16 + (q << 2) + r) * COUT + co] = v;
        sp += v;
        qp = fmaf(v, v, qp);
      }
    }
    sp += __shfl_xor(sp, 16, 64); sp += __shfl_xor(sp, 32, 64);
    qp += __shfl_xor(qp, 16, 64); qp += __shfl_xor(qp, 32, 64);
    if (q == 0) {
      atomicAdd(stat + bk + co, sp);
      atomicAdd(stat + bk + 128 + co, qp);
    }
  }
}

// ------------------------------------------------------------ stage-3 deform conv, S=16
// Cooperative phase A + ping-pong abuf: exactly 1 barrier per tap. fp16 split-A x single-B.
__global__ __launch_bounds__(256, 3) void k_dconv3(
    const float* __restrict__ in, const float* __restrict__ scale,
    const float* __restrict__ shift, const float* __restrict__ w0t,
    const float* __restrict__ obias, const unsigned short* __restrict__ wp,
    float* __restrict__ out, float* __restrict__ stat) {
  constexpr int CIN = 128, H = 8, W = 8, STRIDE = 2, HO = 4, WO = 4, COUT = 128;
  constexpr int S = 16, HW = 64, CP = CIN + 4, AP = CIN + 8;
  constexpr int NCT = 8, KS = 4;

  __shared__ float tile[HW * CP];
  __shared__ float offs[18 * 16];
  __shared__ unsigned short abuf[2][2 * 16 * AP];

  int b = blockIdx.x, t = threadIdx.x;

  const float* inb = in + (size_t)b * CIN * HW;
  for (int i = t; i < HW * CIN / 4; i += 256) {
    int pos = i / (CIN / 4);
    int c4 = (i % (CIN / 4)) * 4;
    float4 v = *(const float4*)&inb[pos * CIN + c4];
    float4 sc = *(const float4*)&scale[c4];
    float4 sh = *(const float4*)&shift[c4];
    float4 o;
    o.x = fmaf(v.x, sc.x, sh.x);
    o.y = fmaf(v.y, sc.y, sh.y);
    o.z = fmaf(v.z, sc.z, sh.z);
    o.w = fmaf(v.w, sc.w, sh.w);
    *(float4*)&tile[pos * CP + c4] = o;
  }
  for (int o = t; o < 288; o += 256) offs[o] = obias[o >> 4];
  __syncthreads();

  int lane = t & 63, w = t >> 6;
  int srow = lane & 15, q = lane >> 4;

  // ---- phase 0: offset conv, 16 reps of 8 ci; shuffle + LDS-atomic reduce
  {
    int s0 = t & 15;
    int rep = t >> 4;
    int ho = s0 >> 2, wo = s0 & 3;
    int ci0 = rep * 8;
    float a0[18];
#pragma unroll
    for (int c = 0; c < 18; c++) a0[c] = 0.0f;
    for (int k = 0; k < 9; k++) {
      int y = ho * STRIDE - 1 + k / 3;
      int x = wo * STRIDE - 1 + k % 3;
      bool valid = ((unsigned)y < (unsigned)H) && ((unsigned)x < (unsigned)W);
      int pos = valid ? y * W + x : 0;
#pragma unroll
      for (int g = 0; g < 2; g++) {
        int ci = ci0 + g * 4;
        float4 f = *(const float4*)&tile[pos * CP + ci];
        float tv[4] = {f.x, f.y, f.z, f.w};
        if (!valid) { tv[0] = tv[1] = tv[2] = tv[3] = 0.0f; }
        const float* wpo = w0t + (k * CIN + ci) * 18;
#pragma unroll
        for (int j = 0; j < 4; j++)
#pragma unroll
          for (int c = 0; c < 18; c++)
            a0[c] = fmaf(tv[j], wpo[j * 18 + c], a0[c]);
      }
    }
#pragma unroll
    for (int c = 0; c < 18; c++) {
      a0[c] += __shfl_xor(a0[c], 16, 64);
      a0[c] += __shfl_xor(a0[c], 32, 64);
    }
    if (q == 0) {
#pragma unroll
      for (int c = 0; c < 18; c++) atomicAdd(&offs[c * 16 + srow], a0[c]);
    }
  }
  __syncthreads();

  // ---- main loop: ping-pong A buffer, 1 barrier per tap
  int ct0 = w * 2;
  f32x4 acc[2];
  acc[0] = (f32x4){0.f, 0.f, 0.f, 0.f};
  acc[1] = (f32x4){0.f, 0.f, 0.f, 0.f};

  int sA = t & 15;
  int repA = t >> 4;
  int hoA = sA >> 2, woA = sA & 3;
  int ciA = repA * 8;
  int p = 0;

  for (int k = 0; k < 9; k++) {
    {
      float dy = offs[(2 * k) * 16 + sA];
      float dx = offs[(2 * k + 1) * 16 + sA];
      float py = (float)(hoA * STRIDE - 1 + k / 3) + dy;
      float px = (float)(woA * STRIDE - 1 + k % 3) + dx;
      float w00, w01, w10, w11;
      int p00, p01, p10, p11;
      bilin_setup<H, W>(py, px, w00, w01, w10, w11, p00, p01, p10, p11, CP);
      unsigned short* ab = abuf[p];
#pragma unroll
      for (int g = 0; g < 2; g++) {
        int ci = ciA + g * 4;
        float4 f00 = *(const float4*)&tile[p00 + ci];
        float4 f01 = *(const float4*)&tile[p01 + ci];
        float4 f10 = *(const float4*)&tile[p10 + ci];
        float4 f11 = *(const float4*)&tile[p11 + ci];
        float v0 = w00 * f00.x + w01 * f01.x + w10 * f10.x + w11 * f11.x;
        float v1 = w00 * f00.y + w01 * f01.y + w10 * f10.y + w11 * f11.y;
        float v2 = w00 * f00.z + w01 * f01.z + w10 * f10.z + w11 * f11.z;
        float v3 = w00 * f00.w + w01 * f01.w + w10 * f10.w + w11 * f11.w;
        ushort4 h, l;
        h.x = f2h(v0); l.x = f2h(v0 - h2f(h.x));
        h.y = f2h(v1); l.y = f2h(v1 - h2f(h.y));
        h.z = f2h(v2); l.z = f2h(v2 - h2f(h.z));
        h.w = f2h(v3); l.w = f2h(v3 - h2f(h.w));
        *(ushort4*)&ab[sA * AP + ci] = h;
        *(ushort4*)&ab[16 * AP + sA * AP + ci] = l;
      }
    }
    __syncthreads();
    const unsigned short* wk = wp + (size_t)k * KS * NCT * 512;
    const unsigned short* ab = abuf[p];
#pragma unroll
    for (int ks = 0; ks < KS; ks++) {
      f16x8 ah = *(const f16x8*)&ab[srow * AP + ks * 32 + q * 8];
      f16x8 al = *(const f16x8*)&ab[16 * AP + srow * AP + ks * 32 + q * 8];
#pragma unroll
      for (int ctl = 0; ctl < 2; ctl++) {
        int ct = ct0 + ctl;
        const f16x8 bv = *(const f16x8*)&wk[((ks * NCT + ct) * 64 + lane) * 8];
        acc[ctl] = __builtin_amdgcn_mfma_f32_16x16x32_f16(ah, bv, acc[ctl], 0, 0, 0);
        acc[ctl] = __builtin_amdgcn_mfma_f32_16x16x32_f16(al, bv, acc[ctl], 0, 0, 0);
      }
    }
    p ^= 1;
  }

  // ---- epilogue: relu + store + fused BN stats
  float* ob = out + (size_t)b * S * COUT;
  int bk = (b & 7) * 256;
#pragma unroll
  for (int ctl = 0; ctl < 2; ctl++) {
    int co = (ct0 + ctl) * 16 + srow;
    int sr = q << 2;
    float sp = 0.0f, qp = 0.0f;
#pragma unroll
    for (int r = 0; r < 4; r++) {
      float v = fmaxf(acc[ctl][r], 0.0f);
      ob[(sr + r) * COUT + co] = v;
      sp += v;
      qp = fmaf(v, v, qp);
    }
    sp += __shfl_xor(sp, 16, 64); sp += __shfl_xor(sp, 32, 64);
    qp += __shfl_xor(qp, 16, 64); qp += __shfl_xor(qp, 32, 64);
    if (q == 0) {
      atomicAdd(stat + bk + co, sp);
      atomicAdd(stat + bk + 128 + co, qp);
    }
  }
}

// ------------------------------------------------------------ pool + fc  (h4: [b][s][128])
__global__ __launch_bounds__(128) void k_poolfc(
    const float* __restrict__ h4, const float* __restrict__ scale,
    const float* __restrict__ shift, const float* __restrict__ fcw,
    const float* __restrict__ fcb, float* __restrict__ out) {
  __shared__ float pooled[128];
  int b = blockIdx.x;
  int c = threadIdx.x;
  const float* hb = h4 + (size_t)b * 2048;
  float sm = 0.0f;
#pragma unroll
  for (int s = 0; s < 16; s++) sm += hb[s * 128 + c];
  pooled[c] = fmaf(sm * (1.0f / 16.0f), scale[c], shift[c]);
  __syncthreads();
  if (c < 10) {
    float acc = fcb[c];
#pragma unroll
    for (int i = 0; i < 128; i++) acc = fmaf(pooled[i], fcw[c * 128 + i], acc);
    out[(size_t)b * 10 + c] = acc;
  }
}

// ---------------------------------------------------------------- launch
extern "C" void kernel_launch(void* const* d_in, const int* in_sizes, int n_in,
                              void* d_out, int out_size, void* d_ws, size_t ws_size,
                              hipStream_t stream) {
  const float* x       = (const float*)d_in[0];
  const float* conv1_w = (const float*)d_in[1];
  const float* conv1_b = (const float*)d_in[2];
  const float* bn1_g   = (const float*)d_in[3];
  const float* bn1_b   = (const float*)d_in[4];
  const float* off1_w  = (const float*)d_in[5];
  const float* off1_b  = (const float*)d_in[6];
  const float* dc1_w   = (const float*)d_in[7];
  const float* bn2_g   = (const float*)d_in[8];
  const float* bn2_b   = (const float*)d_in[9];
  const float* off2_w  = (const float*)d_in[10];
  const float* off2_b  = (const float*)d_in[11];
  const float* dc2_w   = (const float*)d_in[12];
  const float* bn3_g   = (const float*)d_in[13];
  const float* bn3_b   = (const float*)d_in[14];
  const float* off3_w  = (const float*)d_in[15];
  const float* off3_b  = (const float*)d_in[16];
  const float* dc3_w   = (const float*)d_in[17];
  const float* bn4_g   = (const float*)d_in[18];
  const float* bn4_b   = (const float*)d_in[19];
  const float* fc_w    = (const float*)d_in[20];
  const float* fc_b    = (const float*)d_in[21];
  float* out = (float*)d_out;

  float* wsf = (float*)d_ws;
  // region A: h1 [2048][256][32] / h3 [2048][64][128] alias — 16777216 floats
  float* h1 = wsf;
  float* h3 = wsf;
  // region B: h2 [2048][64][64] / h4 [2048][16][128] alias — 8388608 floats
  float* h2 = wsf + 16777216;
  float* h4 = wsf + 16777216;
  float* wbase = wsf + 25165824;
  unsigned short* wp1 = (unsigned short*)wbase;   // fp16 dc packs
  unsigned short* wp2 = wp1 + 18432;
  unsigned short* wp3 = wp2 + 73728;              // total 239616 ushorts = 119808 floats
  float* w0t1 = wbase + 119808;                   // 5184 floats
  float* w0t2 = w0t1 + 5184;                      // 10368
  float* w0t3 = w0t2 + 10368;                     // 20736
  // stats: per stage bucketed sums [8][2][128] (2048 floats) x 4 stages, then sc/sh
  float* stat0 = wbase + 119808 + 36288;
  float* stat1 = stat0 + 2048;
  float* stat2 = stat1 + 2048;
  float* stat3 = stat2 + 2048;
  float* scsh  = stat0 + 8192;
  float* sc1 = scsh + 0,    *sh1 = scsh + 128;
  float* sc2 = scsh + 256,  *sh2 = scsh + 384;
  float* sc3 = scsh + 512,  *sh3 = scsh + 640;
  float* sc4 = scsh + 768,  *sh4 = scsh + 896;

  hipMemsetAsync(stat0, 0, 8192 * sizeof(float), stream);
  k_prep<<<1078, 256, 0, stream>>>(dc1_w, dc2_w, dc3_w, off1_w, off2_w, off3_w,
                                   wp1, wp2, wp3, w0t1, w0t2, w0t3);

  // stage 1
  k_conv1<<<BATCH, 256, 0, stream>>>(x, conv1_w, conv1_b, h1, stat0);
  k_bnfin<<<1, 128, 0, stream>>>(stat0, bn1_g, bn1_b, sc1, sh1, 32, 1.0f / 524288.0f);
  k_dconv12<32, 16, 16, 2, 8, 8, 64, 3><<<BATCH, 256, 0, stream>>>(
      h1, sc1, sh1, w0t1, off1_b, wp1, h2, stat1);

  // stage 2
  k_bnfin<<<1, 128, 0, stream>>>(stat1, bn2_g, bn2_b, sc2, sh2, 64, 1.0f / 131072.0f);
  k_dconv12<64, 8, 8, 1, 8, 8, 128, 4><<<BATCH, 256, 0, stream>>>(
      h2, sc2, sh2, w0t2, off2_b, wp2, h3, stat2);

  // stage 3
  k_bnfin<<<1, 128, 0, stream>>>(stat2, bn3_g, bn3_b, sc3, sh3, 128, 1.0f / 131072.0f);
  k_dconv3<<<BATCH, 256, 0, stream>>>(
      h3, sc3, sh3, w0t3, off3_b, wp3, h4, stat3);

  // stage 4
  k_bnfin<<<1, 128, 0, stream>>>(stat3, bn4_g, bn4_b, sc4, sh4, 128, 1.0f / 32768.0f);
  k_poolfc<<<BATCH, 128, 0, stream>>>(h4, sc4, sh4, fc_w, fc_b, out);
}

// Round 10
// 375.079 us; speedup vs baseline: 41.6442x; 1.2555x over previous
//
#include <hip/hip_runtime.h>

#define BATCH 2048

typedef _Float16 f16;
typedef __attribute__((ext_vector_type(8))) f16 f16x8;
typedef __attribute__((ext_vector_type(4))) f16 f16x4;
typedef __attribute__((ext_vector_type(4))) float f32x4;

__device__ inline unsigned short f2h(float f) {
  union { f16 h; unsigned short u; } v;
  v.h = (f16)f;
  return v.u;
}

// -------------------------------------------------- conv1 + bias + relu + bn1 stats
// out layout: [b][pos(256)][co(32)]; stats -> bucketed [8][2][128]
__global__ __launch_bounds__(256) void k_conv1(
    const float* __restrict__ x, const float* __restrict__ w,
    const float* __restrict__ bias, float* __restrict__ out,
    float* __restrict__ stat) {
  __shared__ float xs[324];
  __shared__ float wsm[288];
  __shared__ float red[512];
  int b = blockIdx.x, t = threadIdx.x;
  const float* xb = x + (size_t)b * 324;
  for (int i = t; i < 324; i += 256) xs[i] = xb[i];
  for (int i = t; i < 288; i += 256) wsm[i] = w[i];
  __syncthreads();
  int co = t & 31, pp = t >> 5;
  float wv[9];
#pragma unroll
  for (int k = 0; k < 9; k++) wv[k] = wsm[co * 9 + k];
  float bb = bias[co];
  float sp = 0.0f, qp = 0.0f;
  float* ob = out + (size_t)b * 8192;
  for (int i = 0; i < 32; i++) {
    int pos = (i << 3) + pp;
    int ho = pos >> 4, wo = pos & 15;
    float a = bb;
#pragma unroll
    for (int ki = 0; ki < 3; ki++)
#pragma unroll
      for (int kj = 0; kj < 3; kj++)
        a = fmaf(xs[(ho + ki) * 18 + wo + kj], wv[ki * 3 + kj], a);
    a = fmaxf(a, 0.0f);
    ob[pos * 32 + co] = a;
    sp += a;
    qp = fmaf(a, a, qp);
  }
  red[t] = sp;
  red[256 + t] = qp;
  __syncthreads();
  if (t < 32) {
    float S = 0.0f, Q = 0.0f;
#pragma unroll
    for (int r = 0; r < 8; r++) {
      S += red[r * 32 + t];
      Q += red[256 + r * 32 + t];
    }
    int bk = (b & 7) * 256;
    atomicAdd(stat + bk + t, S);
    atomicAdd(stat + bk + 128 + t, Q);
  }
}

// ------------------------------------------------------------ bn finalize (bucketed)
__global__ void k_bnfin(const float* __restrict__ st,
                        const float* __restrict__ g, const float* __restrict__ beta,
                        float* __restrict__ scale, float* __restrict__ shift,
                        int C, float invN) {
  int c = threadIdx.x;
  if (c < C) {
    float m = 0.0f, v = 0.0f;
#pragma unroll
    for (int j = 0; j < 8; j++) {
      m += st[j * 256 + c];
      v += st[j * 256 + 128 + c];
    }
    m *= invN;
    v = v * invN - m * m;
    float sc = rsqrtf(v + 1e-5f) * g[c];
    scale[c] = sc;
    shift[c] = beta[c] - m * sc;
  }
}

// ------------------------------------------------------------ weight prep
// dc weights -> fp16 B-fragment pack [tap][ks][ct][lane][8]:
//   ci = ks*32 + (lane>>4)*8 + j ; co = ct*16 + (lane&15)
// off weights (stages 1,2) -> fp16 B-fragment pack [tap][ks][ct(2)][lane][8], co<18 else 0
// off weights (stage 3)    -> fp32 [k][ci][18]
__global__ __launch_bounds__(256) void k_prep(
    const float* __restrict__ dc1, const float* __restrict__ dc2,
    const float* __restrict__ dc3, const float* __restrict__ ow1,
    const float* __restrict__ ow2, const float* __restrict__ ow3,
    unsigned short* __restrict__ wp1, unsigned short* __restrict__ wp2,
    unsigned short* __restrict__ wp3, unsigned short* __restrict__ w0p1,
    unsigned short* __restrict__ w0p2, float* __restrict__ w0t3) {
  int idx = blockIdx.x * 256 + threadIdx.x;
  if (idx < 239616) {
    int e = idx;
    const float* src; unsigned short* dst; int CIN, NCT, KS;
    if (e < 18432)      { src = dc1; dst = wp1; CIN = 32;  NCT = 4; KS = 1; }
    else if (e < 92160) { e -= 18432; src = dc2; dst = wp2; CIN = 64;  NCT = 8; KS = 2; }
    else                { e -= 92160; src = dc3; dst = wp3; CIN = 128; NCT = 8; KS = 4; }
    int j = e & 7, lane = (e >> 3) & 63;
    int rest = e >> 9;
    int ct = rest % NCT; rest /= NCT;
    int ks = rest % KS;
    int tap = rest / KS;
    int ci = ks * 32 + ((lane >> 4) << 3) + j;
    int co = ct * 16 + (lane & 15);
    dst[e] = f2h(src[((size_t)co * CIN + ci) * 9 + tap]);
  } else if (idx < 267264) {
    int e = idx - 239616;
    const float* src; unsigned short* dst; int CIN, KS;
    if (e < 9216) { src = ow1; dst = w0p1; CIN = 32; KS = 1; }
    else          { e -= 9216; src = ow2; dst = w0p2; CIN = 64; KS = 2; }
    int j = e & 7, lane = (e >> 3) & 63;
    int rest = e >> 9;
    int ct = rest & 1; rest >>= 1;
    int ks = rest % KS;
    int tap = rest / KS;
    int ci = ks * 32 + ((lane >> 4) << 3) + j;
    int co = ct * 16 + (lane & 15);
    dst[e] = (co < 18) ? f2h(src[((size_t)co * CIN + ci) * 9 + tap])
                       : (unsigned short)0;
  } else if (idx < 288000) {
    int e = idx - 267264;
    int co = e % 18;
    int r = e / 18;
    int ci = r % 128;
    int k = r / 128;
    w0t3[e] = ow3[((size_t)co * 128 + ci) * 9 + k];
  }
}

// ------------------------------------------------------------ bilinear helper
template <int H, int W>
__device__ inline void bilin_setup(float py, float px, float& w00, float& w01,
                                   float& w10, float& w11, int& p00, int& p01,
                                   int& p10, int& p11, int CP) {
  float y0f = floorf(py), x0f = floorf(px);
  float wy = py - y0f, wx = px - x0f;
  int y0 = (int)y0f, x0 = (int)x0f, y1 = y0 + 1, x1 = x0 + 1;
  w00 = (1.0f - wy) * (1.0f - wx);
  w01 = (1.0f - wy) * wx;
  w10 = wy * (1.0f - wx);
  w11 = wy * wx;
  bool vy0 = (unsigned)y0 < (unsigned)H, vy1 = (unsigned)y1 < (unsigned)H;
  bool vx0 = (unsigned)x0 < (unsigned)W, vx1 = (unsigned)x1 < (unsigned)W;
  w00 = (vy0 && vx0) ? w00 : 0.0f;
  w01 = (vy0 && vx1) ? w01 : 0.0f;
  w10 = (vy1 && vx0) ? w10 : 0.0f;
  w11 = (vy1 && vx1) ? w11 : 0.0f;
  int yc0 = min(max(y0, 0), H - 1) * W, yc1 = min(max(y1, 0), H - 1) * W;
  int xc0 = min(max(x0, 0), W - 1),     xc1 = min(max(x1, 0), W - 1);
  p00 = (yc0 + xc0) * CP; p01 = (yc0 + xc1) * CP;
  p10 = (yc1 + xc0) * CP; p11 = (yc1 + xc1) * CP;
}

// ------------------------------------------------------------ fused offsetconv + deform conv, S=64
// FULLY wave-independent after tile staging (1 block barrier total):
//  - phase 0: offset conv via MFMA, wave-private rows, offs written without atomics
//  - main loop: fp16 split-A (hi+lo) x fp16 single-B MFMA, private abuf slice
// LDS A-buffer is f16-typed end-to-end (stores f16x4, loads f16x8) so the compiler
// cannot TBAA-reorder the MFMA ds_reads above the staging ds_writes (R8 bug);
// empty asm memory fences pin the order as well.
template <int CIN, int H, int W, int STRIDE, int HO, int WO, int COUT, int MINB>
__global__ __launch_bounds__(256, MINB) void k_dconv12(
    const float* __restrict__ in, const float* __restrict__ scale,
    const float* __restrict__ shift, const unsigned short* __restrict__ w0p,
    const float* __restrict__ obias, const unsigned short* __restrict__ wp,
    float* __restrict__ out, float* __restrict__ stat) {
  constexpr int S   = HO * WO;          // 64
  constexpr int HW  = H * W;
  constexpr int CP  = CIN + 4;          // fp32 tile row stride
  constexpr int AP  = CIN + 8;          // A-buffer row stride (f16 elems)
  constexpr int CQ  = CIN / 4;          // ci per lane-quarter
  constexpr int NCT = COUT / 16;
  constexpr int KS  = CIN / 32;
  static_assert(S == 64 && CQ % 4 == 0, "geometry");

  __shared__ float tile[HW * CP];
  __shared__ float offs[18 * 64];
  __shared__ f16 abuf[4 * 2 * 16 * AP];  // per wave: hi plane, lo plane

  int b = blockIdx.x, t = threadIdx.x;

  // ---- stage BN'd input as fp32 [pos][ci]
  const float* inb = in + (size_t)b * CIN * HW;
  for (int i = t; i < HW * CIN / 4; i += 256) {
    int pos = i / (CIN / 4);
    int c4 = (i % (CIN / 4)) * 4;
    float4 v = *(const float4*)&inb[pos * CIN + c4];
    float4 sc = *(const float4*)&scale[c4];
    float4 sh = *(const float4*)&shift[c4];
    float4 o;
    o.x = fmaf(v.x, sc.x, sh.x);
    o.y = fmaf(v.y, sc.y, sh.y);
    o.z = fmaf(v.z, sc.z, sh.z);
    o.w = fmaf(v.w, sc.w, sh.w);
    *(float4*)&tile[pos * CP + c4] = o;
  }
  __syncthreads();
  // ======== the ONLY block barrier — everything below is wave-independent ========

  int lane = t & 63, w = t >> 6;
  int srow = lane & 15, q = lane >> 4;
  int s = w * 16 + srow;                // output row this thread stages
  int ho_a = s / WO, wo_a = s % WO;
  int ciA = q * CQ;
  f16* hbuf = abuf + w * (2 * 16 * AP);
  f16* lbuf = hbuf + 16 * AP;

  // ---- phase 0: offset conv via MFMA (integer taps, fp16 single precision)
  {
    f32x4 oacc[2];
    oacc[0] = (f32x4){0.f, 0.f, 0.f, 0.f};
    oacc[1] = (f32x4){0.f, 0.f, 0.f, 0.f};
    for (int k = 0; k < 9; k++) {
      int y = ho_a * STRIDE - 1 + k / 3;
      int x = wo_a * STRIDE - 1 + k % 3;
      bool valid = ((unsigned)y < (unsigned)H) && ((unsigned)x < (unsigned)W);
      int pos = valid ? y * W + x : 0;
      asm volatile("" ::: "memory");   // prev-tap reads before new writes
#pragma unroll
      for (int g = 0; g < CQ / 4; g++) {
        int ci = ciA + g * 4;
        float4 f = *(const float4*)&tile[pos * CP + ci];
        f16x4 hv;
        hv.x = (f16)(valid ? f.x : 0.0f);
        hv.y = (f16)(valid ? f.y : 0.0f);
        hv.z = (f16)(valid ? f.z : 0.0f);
        hv.w = (f16)(valid ? f.w : 0.0f);
        *(f16x4*)&hbuf[srow * AP + ci] = hv;
      }
      asm volatile("" ::: "memory");   // writes before MFMA reads
      const unsigned short* wk0 = w0p + (size_t)k * KS * 2 * 512;
#pragma unroll
      for (int ks = 0; ks < KS; ks++) {
        f16x8 av = *(const f16x8*)&hbuf[srow * AP + ks * 32 + q * 8];
#pragma unroll
        for (int ct = 0; ct < 2; ct++) {
          const f16x8 bv = *(const f16x8*)&wk0[((ks * 2 + ct) * 64 + lane) * 8];
          oacc[ct] = __builtin_amdgcn_mfma_f32_16x16x32_f16(av, bv, oacc[ct], 0, 0, 0);
        }
      }
    }
    // offs[co][w*16 + m]: C-frag col = lane&15 -> co, row m = q*4+r (wave-private rows)
#pragma unroll
    for (int ct = 0; ct < 2; ct++) {
      int co = ct * 16 + srow;
      if (co < 18) {
        float bb = obias[co];
#pragma unroll
        for (int r = 0; r < 4; r++)
          offs[co * 64 + w * 16 + q * 4 + r] = oacc[ct][r] + bb;
      }
    }
  }

  // ---- main loop over 9 taps (wave-private; f16-typed LDS + fences for ordering)
  f32x4 acc[NCT];
#pragma unroll
  for (int ct = 0; ct < NCT; ct++) acc[ct] = (f32x4){0.f, 0.f, 0.f, 0.f};

  for (int k = 0; k < 9; k++) {
    asm volatile("" ::: "memory");     // prev-tap reads before new writes
    {
      float dy = offs[(2 * k) * 64 + s];
      float dx = offs[(2 * k + 1) * 64 + s];
      float py = (float)(ho_a * STRIDE - 1 + k / 3) + dy;
      float px = (float)(wo_a * STRIDE - 1 + k % 3) + dx;
      float w00, w01, w10, w11;
      int p00, p01, p10, p11;
      bilin_setup<H, W>(py, px, w00, w01, w10, w11, p00, p01, p10, p11, CP);
#pragma unroll
      for (int g = 0; g < CQ / 4; g++) {
        int ci = ciA + g * 4;
        float4 f00 = *(const float4*)&tile[p00 + ci];
        float4 f01 = *(const float4*)&tile[p01 + ci];
        float4 f10 = *(const float4*)&tile[p10 + ci];
        float4 f11 = *(const float4*)&tile[p11 + ci];
        float v0 = w00 * f00.x + w01 * f01.x + w10 * f10.x + w11 * f11.x;
        float v1 = w00 * f00.y + w01 * f01.y + w10 * f10.y + w11 * f11.y;
        float v2 = w00 * f00.z + w01 * f01.z + w10 * f10.z + w11 * f11.z;
        float v3 = w00 * f00.w + w01 * f01.w + w10 * f10.w + w11 * f11.w;
        f16x4 hv, lv;
        hv.x = (f16)v0; lv.x = (f16)(v0 - (float)hv.x);
        hv.y = (f16)v1; lv.y = (f16)(v1 - (float)hv.y);
        hv.z = (f16)v2; lv.z = (f16)(v2 - (float)hv.z);
        hv.w = (f16)v3; lv.w = (f16)(v3 - (float)hv.w);
        *(f16x4*)&hbuf[srow * AP + ci] = hv;
        *(f16x4*)&lbuf[srow * AP + ci] = lv;
      }
    }
    asm volatile("" ::: "memory");     // writes before MFMA reads
    const unsigned short* wk = wp + (size_t)k * KS * NCT * 512;
#pragma unroll
    for (int ks = 0; ks < KS; ks++) {
      f16x8 ah = *(const f16x8*)&hbuf[srow * AP + ks * 32 + q * 8];
      f16x8 al = *(const f16x8*)&lbuf[srow * AP + ks * 32 + q * 8];
#pragma unroll
      for (int ct = 0; ct < NCT; ct++) {
        const f16x8 bv = *(const f16x8*)&wk[((ks * NCT + ct) * 64 + lane) * 8];
        acc[ct] = __builtin_amdgcn_mfma_f32_16x16x32_f16(ah, bv, acc[ct], 0, 0, 0);
        acc[ct] = __builtin_amdgcn_mfma_f32_16x16x32_f16(al, bv, acc[ct], 0, 0, 0);
      }
    }
  }

  // ---- epilogue: relu + store + fused BN stats
  float* ob = out + (size_t)b * S * COUT;
  int bk = (b & 7) * 256;
#pragma unroll
  for (int ct = 0; ct < NCT; ct++) {
    int co = ct * 16 + srow;
    int sr = w * 16 + (q << 2);
    float sp = 0.0f, qp = 0.0f;
#pragma unroll
    for (int r = 0; r < 4; r++) {
      float v = fmaxf(acc[ct][r], 0.0f);
      ob[(sr + r) * COUT + co] = v;
      sp += v;
      qp = fmaf(v, v, qp);
    }
    sp += __shfl_xor(sp, 16, 64); sp += __shfl_xor(sp, 32, 64);
    qp += __shfl_xor(qp, 16, 64); qp += __shfl_xor(qp, 32, 64);
    if (q == 0) {
      atomicAdd(stat + bk + co, sp);
      atomicAdd(stat + bk + 128 + co, qp);
    }
  }
}

// ------------------------------------------------------------ stage-3 deform conv, S=16
// Cooperative phase A + ping-pong abuf: exactly 1 barrier per tap (barrier = fence).
__global__ __launch_bounds__(256, 3) void k_dconv3(
    const float* __restrict__ in, const float* __restrict__ scale,
    const float* __restrict__ shift, const float* __restrict__ w0t,
    const float* __restrict__ obias, const unsigned short* __restrict__ wp,
    float* __restrict__ out, float* __restrict__ stat) {
  constexpr int CIN = 128, H = 8, W = 8, STRIDE = 2, HO = 4, WO = 4, COUT = 128;
  constexpr int S = 16, HW = 64, CP = CIN + 4, AP = CIN + 8;
  constexpr int NCT = 8, KS = 4;

  __shared__ float tile[HW * CP];
  __shared__ float offs[18 * 16];
  __shared__ f16 abuf[2][2 * 16 * AP];

  int b = blockIdx.x, t = threadIdx.x;

  const float* inb = in + (size_t)b * CIN * HW;
  for (int i = t; i < HW * CIN / 4; i += 256) {
    int pos = i / (CIN / 4);
    int c4 = (i % (CIN / 4)) * 4;
    float4 v = *(const float4*)&inb[pos * CIN + c4];
    float4 sc = *(const float4*)&scale[c4];
    float4 sh = *(const float4*)&shift[c4];
    float4 o;
    o.x = fmaf(v.x, sc.x, sh.x);
    o.y = fmaf(v.y, sc.y, sh.y);
    o.z = fmaf(v.z, sc.z, sh.z);
    o.w = fmaf(v.w, sc.w, sh.w);
    *(float4*)&tile[pos * CP + c4] = o;
  }
  for (int o = t; o < 288; o += 256) offs[o] = obias[o >> 4];
  __syncthreads();

  int lane = t & 63, w = t >> 6;
  int srow = lane & 15, q = lane >> 4;

  // ---- phase 0: offset conv, 16 reps of 8 ci; shuffle + LDS-atomic reduce
  {
    int s0 = t & 15;
    int rep = t >> 4;
    int ho = s0 >> 2, wo = s0 & 3;
    int ci0 = rep * 8;
    float a0[18];
#pragma unroll
    for (int c = 0; c < 18; c++) a0[c] = 0.0f;
    for (int k = 0; k < 9; k++) {
      int y = ho * STRIDE - 1 + k / 3;
      int x = wo * STRIDE - 1 + k % 3;
      bool valid = ((unsigned)y < (unsigned)H) && ((unsigned)x < (unsigned)W);
      int pos = valid ? y * W + x : 0;
#pragma unroll
      for (int g = 0; g < 2; g++) {
        int ci = ci0 + g * 4;
        float4 f = *(const float4*)&tile[pos * CP + ci];
        float tv[4] = {f.x, f.y, f.z, f.w};
        if (!valid) { tv[0] = tv[1] = tv[2] = tv[3] = 0.0f; }
        const float* wpo = w0t + (k * CIN + ci) * 18;
#pragma unroll
        for (int j = 0; j < 4; j++)
#pragma unroll
          for (int c = 0; c < 18; c++)
            a0[c] = fmaf(tv[j], wpo[j * 18 + c], a0[c]);
      }
    }
#pragma unroll
    for (int c = 0; c < 18; c++) {
      a0[c] += __shfl_xor(a0[c], 16, 64);
      a0[c] += __shfl_xor(a0[c], 32, 64);
    }
    if (q == 0) {
#pragma unroll
      for (int c = 0; c < 18; c++) atomicAdd(&offs[c * 16 + srow], a0[c]);
    }
  }
  __syncthreads();

  // ---- main loop: ping-pong A buffer, 1 barrier per tap
  int ct0 = w * 2;
  f32x4 acc[2];
  acc[0] = (f32x4){0.f, 0.f, 0.f, 0.f};
  acc[1] = (f32x4){0.f, 0.f, 0.f, 0.f};

  int sA = t & 15;
  int repA = t >> 4;
  int hoA = sA >> 2, woA = sA & 3;
  int ciA = repA * 8;
  int p = 0;

  for (int k = 0; k < 9; k++) {
    {
      float dy = offs[(2 * k) * 16 + sA];
      float dx = offs[(2 * k + 1) * 16 + sA];
      float py = (float)(hoA * STRIDE - 1 + k / 3) + dy;
      float px = (float)(woA * STRIDE - 1 + k % 3) + dx;
      float w00, w01, w10, w11;
      int p00, p01, p10, p11;
      bilin_setup<H, W>(py, px, w00, w01, w10, w11, p00, p01, p10, p11, CP);
      f16* ab = abuf[p];
#pragma unroll
      for (int g = 0; g < 2; g++) {
        int ci = ciA + g * 4;
        float4 f00 = *(const float4*)&tile[p00 + ci];
        float4 f01 = *(const float4*)&tile[p01 + ci];
        float4 f10 = *(const float4*)&tile[p10 + ci];
        float4 f11 = *(const float4*)&tile[p11 + ci];
        float v0 = w00 * f00.x + w01 * f01.x + w10 * f10.x + w11 * f11.x;
        float v1 = w00 * f00.y + w01 * f01.y + w10 * f10.y + w11 * f11.y;
        float v2 = w00 * f00.z + w01 * f01.z + w10 * f10.z + w11 * f11.z;
        float v3 = w00 * f00.w + w01 * f01.w + w10 * f10.w + w11 * f11.w;
        f16x4 hv, lv;
        hv.x = (f16)v0; lv.x = (f16)(v0 - (float)hv.x);
        hv.y = (f16)v1; lv.y = (f16)(v1 - (float)hv.y);
        hv.z = (f16)v2; lv.z = (f16)(v2 - (float)hv.z);
        hv.w = (f16)v3; lv.w = (f16)(v3 - (float)hv.w);
        *(f16x4*)&ab[sA * AP + ci] = hv;
        *(f16x4*)&ab[16 * AP + sA * AP + ci] = lv;
      }
    }
    __syncthreads();
    const unsigned short* wk = wp + (size_t)k * KS * NCT * 512;
    const f16* ab = abuf[p];
#pragma unroll
    for (int ks = 0; ks < KS; ks++) {
      f16x8 ah = *(const f16x8*)&ab[srow * AP + ks * 32 + q * 8];
      f16x8 al = *(const f16x8*)&ab[16 * AP + srow * AP + ks * 32 + q * 8];
#pragma unroll
      for (int ctl = 0; ctl < 2; ctl++) {
        int ct = ct0 + ctl;
        const f16x8 bv = *(const f16x8*)&wk[((ks * NCT + ct) * 64 + lane) * 8];
        acc[ctl] = __builtin_amdgcn_mfma_f32_16x16x32_f16(ah, bv, acc[ctl], 0, 0, 0);
        acc[ctl] = __builtin_amdgcn_mfma_f32_16x16x32_f16(al, bv, acc[ctl], 0, 0, 0);
      }
    }
    p ^= 1;
  }

  // ---- epilogue: relu + store + fused BN stats
  float* ob = out + (size_t)b * S * COUT;
  int bk = (b & 7) * 256;
#pragma unroll
  for (int ctl = 0; ctl < 2; ctl++) {
    int co = (ct0 + ctl) * 16 + srow;
    int sr = q << 2;
    float sp = 0.0f, qp = 0.0f;
#pragma unroll
    for (int r = 0; r < 4; r++) {
      float v = fmaxf(acc[ctl][r], 0.0f);
      ob[(sr + r) * COUT + co] = v;
      sp += v;
      qp = fmaf(v, v, qp);
    }
    sp += __shfl_xor(sp, 16, 64); sp += __shfl_xor(sp, 32, 64);
    qp += __shfl_xor(qp, 16, 64); qp += __shfl_xor(qp, 32, 64);
    if (q == 0) {
      atomicAdd(stat + bk + co, sp);
      atomicAdd(stat + bk + 128 + co, qp);
    }
  }
}

// ------------------------------------------------------------ pool + fc  (h4: [b][s][128])
__global__ __launch_bounds__(128) void k_poolfc(
    const float* __restrict__ h4, const float* __restrict__ scale,
    const float* __restrict__ shift, const float* __restrict__ fcw,
    const float* __restrict__ fcb, float* __restrict__ out) {
  __shared__ float pooled[128];
  int b = blockIdx.x;
  int c = threadIdx.x;
  const float* hb = h4 + (size_t)b * 2048;
  float sm = 0.0f;
#pragma unroll
  for (int s = 0; s < 16; s++) sm += hb[s * 128 + c];
  pooled[c] = fmaf(sm * (1.0f / 16.0f), scale[c], shift[c]);
  __syncthreads();
  if (c < 10) {
    float acc = fcb[c];
#pragma unroll
    for (int i = 0; i < 128; i++) acc = fmaf(pooled[i], fcw[c * 128 + i], acc);
    out[(size_t)b * 10 + c] = acc;
  }
}

// ---------------------------------------------------------------- launch
extern "C" void kernel_launch(void* const* d_in, const int* in_sizes, int n_in,
                              void* d_out, int out_size, void* d_ws, size_t ws_size,
                              hipStream_t stream) {
  const float* x       = (const float*)d_in[0];
  const float* conv1_w = (const float*)d_in[1];
  const float* conv1_b = (const float*)d_in[2];
  const float* bn1_g   = (const float*)d_in[3];
  const float* bn1_b   = (const float*)d_in[4];
  const float* off1_w  = (const float*)d_in[5];
  const float* off1_b  = (const float*)d_in[6];
  const float* dc1_w   = (const float*)d_in[7];
  const float* bn2_g   = (const float*)d_in[8];
  const float* bn2_b   = (const float*)d_in[9];
  const float* off2_w  = (const float*)d_in[10];
  const float* off2_b  = (const float*)d_in[11];
  const float* dc2_w   = (const float*)d_in[12];
  const float* bn3_g   = (const float*)d_in[13];
  const float* bn3_b   = (const float*)d_in[14];
  const float* off3_w  = (const float*)d_in[15];
  const float* off3_b  = (const float*)d_in[16];
  const float* dc3_w   = (const float*)d_in[17];
  const float* bn4_g   = (const float*)d_in[18];
  const float* bn4_b   = (const float*)d_in[19];
  const float* fc_w    = (const float*)d_in[20];
  const float* fc_b    = (const float*)d_in[21];
  float* out = (float*)d_out;

  float* wsf = (float*)d_ws;
  // region A: h1 [2048][256][32] / h3 [2048][64][128] alias — 16777216 floats
  float* h1 = wsf;
  float* h3 = wsf;
  // region B: h2 [2048][64][64] / h4 [2048][16][128] alias — 8388608 floats
  float* h2 = wsf + 16777216;
  float* h4 = wsf + 16777216;
  float* wbase = wsf + 25165824;
  unsigned short* wp1 = (unsigned short*)wbase;   // fp16 dc packs (239616 ushorts)
  unsigned short* wp2 = wp1 + 18432;
  unsigned short* wp3 = wp2 + 73728;
  unsigned short* w0p1 = wp3 + 147456;            // fp16 offset packs
  unsigned short* w0p2 = w0p1 + 9216;             // (9216 + 18432 = 27648 ushorts)
  float* w0t3 = wbase + 119808 + 13824;           // fp32 stage-3 offset weights (20736)
  // stats: per stage bucketed sums [8][2][128] (2048 floats) x 4 stages, then sc/sh
  float* stat0 = wbase + 119808 + 13824 + 20736;
  float* stat1 = stat0 + 2048;
  float* stat2 = stat1 + 2048;
  float* stat3 = stat2 + 2048;
  float* scsh  = stat0 + 8192;
  float* sc1 = scsh + 0,    *sh1 = scsh + 128;
  float* sc2 = scsh + 256,  *sh2 = scsh + 384;
  float* sc3 = scsh + 512,  *sh3 = scsh + 640;
  float* sc4 = scsh + 768,  *sh4 = scsh + 896;

  hipMemsetAsync(stat0, 0, 8192 * sizeof(float), stream);
  k_prep<<<1125, 256, 0, stream>>>(dc1_w, dc2_w, dc3_w, off1_w, off2_w, off3_w,
                                   wp1, wp2, wp3, w0p1, w0p2, w0t3);

  // stage 1
  k_conv1<<<BATCH, 256, 0, stream>>>(x, conv1_w, conv1_b, h1, stat0);
  k_bnfin<<<1, 128, 0, stream>>>(stat0, bn1_g, bn1_b, sc1, sh1, 32, 1.0f / 524288.0f);
  k_dconv12<32, 16, 16, 2, 8, 8, 64, 3><<<BATCH, 256, 0, stream>>>(
      h1, sc1, sh1, w0p1, off1_b, wp1, h2, stat1);

  // stage 2
  k_bnfin<<<1, 128, 0, stream>>>(stat1, bn2_g, bn2_b, sc2, sh2, 64, 1.0f / 131072.0f);
  k_dconv12<64, 8, 8, 1, 8, 8, 128, 4><<<BATCH, 256, 0, stream>>>(
      h2, sc2, sh2, w0p2, off2_b, wp2, h3, stat2);

  // stage 3
  k_bnfin<<<1, 128, 0, stream>>>(stat2, bn3_g, bn3_b, sc3, sh3, 128, 1.0f / 131072.0f);
  k_dconv3<<<BATCH, 256, 0, stream>>>(
      h3, sc3, sh3, w0t3, off3_b, wp3, h4, stat3);

  // stage 4
  k_bnfin<<<1, 128, 0, stream>>>(stat3, bn4_g, bn4_b, sc4, sh4, 128, 1.0f / 32768.0f);
  k_poolfc<<<BATCH, 128, 0, stream>>>(h4, sc4, sh4, fc_w, fc_b, out);
}

// Round 11
// 290.222 us; speedup vs baseline: 53.8204x; 1.2924x over previous
//
#include <hip/hip_runtime.h>

#define BATCH 2048

typedef _Float16 f16;
typedef __attribute__((ext_vector_type(8))) f16 f16x8;
typedef __attribute__((ext_vector_type(4))) float f32x4;

__device__ inline unsigned short f2h(float f) {
  union { f16 h; unsigned short u; } v;
  v.h = (f16)f;
  return v.u;
}

// -------------------------------------------------- conv1 + bias + relu + bn1 stats
// out layout: [b][pos(256)][co(32)]; stats -> bucketed [8][2][128]
__global__ __launch_bounds__(256) void k_conv1(
    const float* __restrict__ x, const float* __restrict__ w,
    const float* __restrict__ bias, float* __restrict__ out,
    float* __restrict__ stat) {
  __shared__ float xs[324];
  __shared__ float wsm[288];
  __shared__ float red[512];
  int b = blockIdx.x, t = threadIdx.x;
  const float* xb = x + (size_t)b * 324;
  for (int i = t; i < 324; i += 256) xs[i] = xb[i];
  for (int i = t; i < 288; i += 256) wsm[i] = w[i];
  __syncthreads();
  int co = t & 31, pp = t >> 5;
  float wv[9];
#pragma unroll
  for (int k = 0; k < 9; k++) wv[k] = wsm[co * 9 + k];
  float bb = bias[co];
  float sp = 0.0f, qp = 0.0f;
  float* ob = out + (size_t)b * 8192;
  for (int i = 0; i < 32; i++) {
    int pos = (i << 3) + pp;
    int ho = pos >> 4, wo = pos & 15;
    float a = bb;
#pragma unroll
    for (int ki = 0; ki < 3; ki++)
#pragma unroll
      for (int kj = 0; kj < 3; kj++)
        a = fmaf(xs[(ho + ki) * 18 + wo + kj], wv[ki * 3 + kj], a);
    a = fmaxf(a, 0.0f);
    ob[pos * 32 + co] = a;
    sp += a;
    qp = fmaf(a, a, qp);
  }
  red[t] = sp;
  red[256 + t] = qp;
  __syncthreads();
  if (t < 32) {
    float S = 0.0f, Q = 0.0f;
#pragma unroll
    for (int r = 0; r < 8; r++) {
      S += red[r * 32 + t];
      Q += red[256 + r * 32 + t];
    }
    int bk = (b & 7) * 256;
    atomicAdd(stat + bk + t, S);
    atomicAdd(stat + bk + 128 + t, Q);
  }
}

// ------------------------------------------------------------ bn finalize (bucketed)
__global__ void k_bnfin(const float* __restrict__ st,
                        const float* __restrict__ g, const float* __restrict__ beta,
                        float* __restrict__ scale, float* __restrict__ shift,
                        int C, float invN) {
  int c = threadIdx.x;
  if (c < C) {
    float m = 0.0f, v = 0.0f;
#pragma unroll
    for (int j = 0; j < 8; j++) {
      m += st[j * 256 + c];
      v += st[j * 256 + 128 + c];
    }
    m *= invN;
    v = v * invN - m * m;
    float sc = rsqrtf(v + 1e-5f) * g[c];
    scale[c] = sc;
    shift[c] = beta[c] - m * sc;
  }
}

// ------------------------------------------------------------ weight prep
// dc weights  -> fp16 B-fragment pack [tap][ks][ct][lane][8]:
//   ci = ks*32 + (lane>>4)*8 + j ; co = ct*16 + (lane&15)
// off weights -> fp16 B-fragment packs [tap][ks][ct(2)][lane][8], co<18 else 0
__global__ __launch_bounds__(256) void k_prep(
    const float* __restrict__ dc1, const float* __restrict__ dc2,
    const float* __restrict__ dc3, const float* __restrict__ ow1,
    const float* __restrict__ ow2, const float* __restrict__ ow3,
    unsigned short* __restrict__ wp1, unsigned short* __restrict__ wp2,
    unsigned short* __restrict__ wp3, unsigned short* __restrict__ w0p1,
    unsigned short* __restrict__ w0p2, unsigned short* __restrict__ w0p3) {
  int idx = blockIdx.x * 256 + threadIdx.x;
  if (idx < 239616) {
    int e = idx;
    const float* src; unsigned short* dst; int CIN, NCT, KS;
    if (e < 18432)      { src = dc1; dst = wp1; CIN = 32;  NCT = 4; KS = 1; }
    else if (e < 92160) { e -= 18432; src = dc2; dst = wp2; CIN = 64;  NCT = 8; KS = 2; }
    else                { e -= 92160; src = dc3; dst = wp3; CIN = 128; NCT = 8; KS = 4; }
    int j = e & 7, lane = (e >> 3) & 63;
    int rest = e >> 9;
    int ct = rest % NCT; rest /= NCT;
    int ks = rest % KS;
    int tap = rest / KS;
    int ci = ks * 32 + ((lane >> 4) << 3) + j;
    int co = ct * 16 + (lane & 15);
    dst[e] = f2h(src[((size_t)co * CIN + ci) * 9 + tap]);
  } else if (idx < 304128) {
    int e = idx - 239616;
    const float* src; unsigned short* dst; int CIN, KS;
    if (e < 9216)       { src = ow1; dst = w0p1; CIN = 32;  KS = 1; }
    else if (e < 27648) { e -= 9216;  src = ow2; dst = w0p2; CIN = 64;  KS = 2; }
    else                { e -= 27648; src = ow3; dst = w0p3; CIN = 128; KS = 4; }
    int j = e & 7, lane = (e >> 3) & 63;
    int rest = e >> 9;
    int ct = rest & 1; rest >>= 1;
    int ks = rest % KS;
    int tap = rest / KS;
    int ci = ks * 32 + ((lane >> 4) << 3) + j;
    int co = ct * 16 + (lane & 15);
    dst[e] = (co < 18) ? f2h(src[((size_t)co * CIN + ci) * 9 + tap])
                       : (unsigned short)0;
  }
}

// ------------------------------------------------------------ bilinear helper
template <int H, int W>
__device__ inline void bilin_setup(float py, float px, float& w00, float& w01,
                                   float& w10, float& w11, int& p00, int& p01,
                                   int& p10, int& p11, int CP) {
  float y0f = floorf(py), x0f = floorf(px);
  float wy = py - y0f, wx = px - x0f;
  int y0 = (int)y0f, x0 = (int)x0f, y1 = y0 + 1, x1 = x0 + 1;
  w00 = (1.0f - wy) * (1.0f - wx);
  w01 = (1.0f - wy) * wx;
  w10 = wy * (1.0f - wx);
  w11 = wy * wx;
  bool vy0 = (unsigned)y0 < (unsigned)H, vy1 = (unsigned)y1 < (unsigned)H;
  bool vx0 = (unsigned)x0 < (unsigned)W, vx1 = (unsigned)x1 < (unsigned)W;
  w00 = (vy0 && vx0) ? w00 : 0.0f;
  w01 = (vy0 && vx1) ? w01 : 0.0f;
  w10 = (vy1 && vx0) ? w10 : 0.0f;
  w11 = (vy1 && vx1) ? w11 : 0.0f;
  int yc0 = min(max(y0, 0), H - 1) * W, yc1 = min(max(y1, 0), H - 1) * W;
  int xc0 = min(max(x0, 0), W - 1),     xc1 = min(max(x1, 0), W - 1);
  p00 = (yc0 + xc0) * CP; p01 = (yc0 + xc1) * CP;
  p10 = (yc1 + xc0) * CP; p11 = (yc1 + xc1) * CP;
}

// build split-fp16 A fragment half (4 elems starting at vector slot g*4) from bilinear
#define BILIN4(ci_)                                                          \
  {                                                                          \
    float4 f00 = *(const float4*)&tile[p00 + (ci_)];                         \
    float4 f01 = *(const float4*)&tile[p01 + (ci_)];                         \
    float4 f10 = *(const float4*)&tile[p10 + (ci_)];                         \
    float4 f11 = *(const float4*)&tile[p11 + (ci_)];                         \
    float v0 = w00 * f00.x + w01 * f01.x + w10 * f10.x + w11 * f11.x;        \
    float v1 = w00 * f00.y + w01 * f01.y + w10 * f10.y + w11 * f11.y;        \
    float v2 = w00 * f00.z + w01 * f01.z + w10 * f10.z + w11 * f11.z;        \
    float v3 = w00 * f00.w + w01 * f01.w + w10 * f10.w + w11 * f11.w;        \
    ah[g * 4 + 0] = (f16)v0; al[g * 4 + 0] = (f16)(v0 - (float)ah[g * 4 + 0]); \
    ah[g * 4 + 1] = (f16)v1; al[g * 4 + 1] = (f16)(v1 - (float)ah[g * 4 + 1]); \
    ah[g * 4 + 2] = (f16)v2; al[g * 4 + 2] = (f16)(v2 - (float)ah[g * 4 + 2]); \
    ah[g * 4 + 3] = (f16)v3; al[g * 4 + 3] = (f16)(v3 - (float)ah[g * 4 + 3]); \
  }

// ------------------------------------------------------------ fused offsetconv + deform conv, S=64
// All-register A fragments (no LDS A-buffer): each lane builds exactly its own
// MFMA fragment (row srow, k = ks*32+q*8..+7). One block barrier total.
template <int CIN, int H, int W, int STRIDE, int HO, int WO, int COUT, int MINB>
__global__ __launch_bounds__(256, MINB) void k_dconv12(
    const float* __restrict__ in, const float* __restrict__ scale,
    const float* __restrict__ shift, const unsigned short* __restrict__ w0p,
    const float* __restrict__ obias, const unsigned short* __restrict__ wp,
    float* __restrict__ out, float* __restrict__ stat) {
  constexpr int S   = HO * WO;          // 64
  constexpr int HW  = H * W;
  constexpr int CP  = CIN + 4;
  constexpr int NCT = COUT / 16;
  constexpr int KS  = CIN / 32;
  static_assert(S == 64, "geometry");

  __shared__ float tile[HW * CP];
  __shared__ float offs[18 * 64];

  int b = blockIdx.x, t = threadIdx.x;

  const float* inb = in + (size_t)b * CIN * HW;
  for (int i = t; i < HW * CIN / 4; i += 256) {
    int pos = i / (CIN / 4);
    int c4 = (i % (CIN / 4)) * 4;
    float4 v = *(const float4*)&inb[pos * CIN + c4];
    float4 sc = *(const float4*)&scale[c4];
    float4 sh = *(const float4*)&shift[c4];
    float4 o;
    o.x = fmaf(v.x, sc.x, sh.x);
    o.y = fmaf(v.y, sc.y, sh.y);
    o.z = fmaf(v.z, sc.z, sh.z);
    o.w = fmaf(v.w, sc.w, sh.w);
    *(float4*)&tile[pos * CP + c4] = o;
  }
  __syncthreads();
  // ======== the ONLY block barrier — everything below is wave-independent ========

  int lane = t & 63, w = t >> 6;
  int srow = lane & 15, q = lane >> 4;
  int s = w * 16 + srow;                // this lane's output row
  int ho_a = s / WO, wo_a = s % WO;

  // ---- phase 0: offset conv via MFMA, register A fragments
  {
    f32x4 oacc[2];
    oacc[0] = (f32x4){0.f, 0.f, 0.f, 0.f};
    oacc[1] = (f32x4){0.f, 0.f, 0.f, 0.f};
    for (int k = 0; k < 9; k++) {
      int y = ho_a * STRIDE - 1 + k / 3;
      int x = wo_a * STRIDE - 1 + k % 3;
      bool valid = ((unsigned)y < (unsigned)H) && ((unsigned)x < (unsigned)W);
      int pos = valid ? y * W + x : 0;
      const unsigned short* wk0 = w0p + (size_t)k * KS * 2 * 512;
#pragma unroll
      for (int ks = 0; ks < KS; ks++) {
        f16x8 av;
#pragma unroll
        for (int g = 0; g < 2; g++) {
          int ci = ks * 32 + q * 8 + g * 4;
          float4 f = *(const float4*)&tile[pos * CP + ci];
          av[g * 4 + 0] = (f16)(valid ? f.x : 0.0f);
          av[g * 4 + 1] = (f16)(valid ? f.y : 0.0f);
          av[g * 4 + 2] = (f16)(valid ? f.z : 0.0f);
          av[g * 4 + 3] = (f16)(valid ? f.w : 0.0f);
        }
#pragma unroll
        for (int ct = 0; ct < 2; ct++) {
          const f16x8 bv = *(const f16x8*)&wk0[(ks * 2 + ct) * 512 + lane * 8];
          oacc[ct] = __builtin_amdgcn_mfma_f32_16x16x32_f16(av, bv, oacc[ct], 0, 0, 0);
        }
      }
    }
    // offs[co][w*16 + m]: C-frag col -> co, row m = q*4+r (wave-private rows)
#pragma unroll
    for (int ct = 0; ct < 2; ct++) {
      int co = ct * 16 + srow;
      if (co < 18) {
        float bb = obias[co];
#pragma unroll
        for (int r = 0; r < 4; r++)
          offs[co * 64 + w * 16 + q * 4 + r] = oacc[ct][r] + bb;
      }
    }
  }

  // ---- main loop over 9 taps (register A fragments)
  f32x4 acc[NCT];
#pragma unroll
  for (int ct = 0; ct < NCT; ct++) acc[ct] = (f32x4){0.f, 0.f, 0.f, 0.f};

  for (int k = 0; k < 9; k++) {
    float dy = offs[(2 * k) * 64 + s];
    float dx = offs[(2 * k + 1) * 64 + s];
    float py = (float)(ho_a * STRIDE - 1 + k / 3) + dy;
    float px = (float)(wo_a * STRIDE - 1 + k % 3) + dx;
    float w00, w01, w10, w11;
    int p00, p01, p10, p11;
    bilin_setup<H, W>(py, px, w00, w01, w10, w11, p00, p01, p10, p11, CP);
    const unsigned short* wk = wp + (size_t)k * KS * NCT * 512;
#pragma unroll
    for (int ks = 0; ks < KS; ks++) {
      f16x8 ah, al;
#pragma unroll
      for (int g = 0; g < 2; g++) {
        int ci = ks * 32 + q * 8 + g * 4;
        BILIN4(ci);
      }
#pragma unroll
      for (int ct = 0; ct < NCT; ct++) {
        const f16x8 bv = *(const f16x8*)&wk[(ks * NCT + ct) * 512 + lane * 8];
        acc[ct] = __builtin_amdgcn_mfma_f32_16x16x32_f16(ah, bv, acc[ct], 0, 0, 0);
        acc[ct] = __builtin_amdgcn_mfma_f32_16x16x32_f16(al, bv, acc[ct], 0, 0, 0);
      }
    }
  }

  // ---- epilogue: relu + store + fused BN stats
  float* ob = out + (size_t)b * S * COUT;
  int bk = (b & 7) * 256;
#pragma unroll
  for (int ct = 0; ct < NCT; ct++) {
    int co = ct * 16 + srow;
    int sr = w * 16 + (q << 2);
    float sp = 0.0f, qp = 0.0f;
#pragma unroll
    for (int r = 0; r < 4; r++) {
      float v = fmaxf(acc[ct][r], 0.0f);
      ob[(sr + r) * COUT + co] = v;
      sp += v;
      qp = fmaf(v, v, qp);
    }
    sp += __shfl_xor(sp, 16, 64); sp += __shfl_xor(sp, 32, 64);
    qp += __shfl_xor(qp, 16, 64); qp += __shfl_xor(qp, 32, 64);
    if (q == 0) {
      atomicAdd(stat + bk + co, sp);
      atomicAdd(stat + bk + 128 + co, qp);
    }
  }
}

// ------------------------------------------------------------ stage-3 deform conv, S=16
// K-split: wave w owns ci [w*32, w*32+32). Register A fragments (each lane's
// staged values ARE its fragment). Phase 0 via MFMA partials + LDS atomics.
// Barrier-free main loop; cross-wave C reduction via LDS (aliases tile). 4 barriers.
__global__ __launch_bounds__(256, 4) void k_dconv3(
    const float* __restrict__ in, const float* __restrict__ scale,
    const float* __restrict__ shift, const unsigned short* __restrict__ w0p,
    const float* __restrict__ obias, const unsigned short* __restrict__ wp,
    float* __restrict__ out, float* __restrict__ stat) {
  constexpr int CIN = 128, H = 8, W = 8, HO = 4, WO = 4, COUT = 128;
  constexpr int HW = 64, CP = CIN + 4;  // 132; tile = 8448 floats (= cred 4*64*33)
  constexpr int NCT = 8, KS = 4;

  __shared__ float tile[HW * CP];
  __shared__ float offs[288];

  int b = blockIdx.x, t = threadIdx.x;

  const float* inb = in + (size_t)b * CIN * HW;
  for (int i = t; i < HW * CIN / 4; i += 256) {
    int pos = i / (CIN / 4);
    int c4 = (i % (CIN / 4)) * 4;
    float4 v = *(const float4*)&inb[pos * CIN + c4];
    float4 sc = *(const float4*)&scale[c4];
    float4 sh = *(const float4*)&shift[c4];
    float4 o;
    o.x = fmaf(v.x, sc.x, sh.x);
    o.y = fmaf(v.y, sc.y, sh.y);
    o.z = fmaf(v.z, sc.z, sh.z);
    o.w = fmaf(v.w, sc.w, sh.w);
    *(float4*)&tile[pos * CP + c4] = o;
  }
  for (int o = t; o < 288; o += 256) offs[o] = obias[o >> 4];
  __syncthreads();  // B1: tile + offs-bias ready

  int lane = t & 63, w = t >> 6;
  int srow = lane & 15, q = lane >> 4;
  int hoA = srow >> 2, woA = srow & 3;   // output row = srow (S=16)

  // ---- phase 0: offset conv partial over this wave's K-chunk (ks = w)
  {
    f32x4 oacc[2];
    oacc[0] = (f32x4){0.f, 0.f, 0.f, 0.f};
    oacc[1] = (f32x4){0.f, 0.f, 0.f, 0.f};
    for (int k = 0; k < 9; k++) {
      int y = hoA * 2 - 1 + k / 3;
      int x = woA * 2 - 1 + k % 3;
      bool valid = ((unsigned)y < (unsigned)H) && ((unsigned)x < (unsigned)W);
      int pos = valid ? y * W + x : 0;
      f16x8 av;
#pragma unroll
      for (int g = 0; g < 2; g++) {
        int ci = w * 32 + q * 8 + g * 4;
        float4 f = *(const float4*)&tile[pos * CP + ci];
        av[g * 4 + 0] = (f16)(valid ? f.x : 0.0f);
        av[g * 4 + 1] = (f16)(valid ? f.y : 0.0f);
        av[g * 4 + 2] = (f16)(valid ? f.z : 0.0f);
        av[g * 4 + 3] = (f16)(valid ? f.w : 0.0f);
      }
      const unsigned short* wk0 = w0p + ((size_t)k * 8 + w * 2) * 512;
#pragma unroll
      for (int ct = 0; ct < 2; ct++) {
        const f16x8 bv = *(const f16x8*)&wk0[ct * 512 + lane * 8];
        oacc[ct] = __builtin_amdgcn_mfma_f32_16x16x32_f16(av, bv, oacc[ct], 0, 0, 0);
      }
    }
#pragma unroll
    for (int ct = 0; ct < 2; ct++) {
      int co = ct * 16 + srow;
      if (co < 18) {
#pragma unroll
        for (int r = 0; r < 4; r++)
          atomicAdd(&offs[co * 16 + q * 4 + r], oacc[ct][r]);
      }
    }
  }
  __syncthreads();  // B2: all K-chunk partials summed into offs

  // ---- main loop: barrier-free, register fragments, partial C over ks=w
  f32x4 acc[NCT];
#pragma unroll
  for (int ct = 0; ct < NCT; ct++) acc[ct] = (f32x4){0.f, 0.f, 0.f, 0.f};

  for (int k = 0; k < 9; k++) {
    float dy = offs[(2 * k) * 16 + srow];
    float dx = offs[(2 * k + 1) * 16 + srow];
    float py = (float)(hoA * 2 - 1 + k / 3) + dy;
    float px = (float)(woA * 2 - 1 + k % 3) + dx;
    float w00, w01, w10, w11;
    int p00, p01, p10, p11;
    bilin_setup<H, W>(py, px, w00, w01, w10, w11, p00, p01, p10, p11, CP);
    f16x8 ah, al;
#pragma unroll
    for (int g = 0; g < 2; g++) {
      int ci = w * 32 + q * 8 + g * 4;
      BILIN4(ci);
    }
    const unsigned short* wk = wp + ((size_t)k * KS * NCT + w * NCT) * 512;
#pragma unroll
    for (int ct = 0; ct < NCT; ct++) {
      const f16x8 bv = *(const f16x8*)&wk[ct * 512 + lane * 8];
      acc[ct] = __builtin_amdgcn_mfma_f32_16x16x32_f16(ah, bv, acc[ct], 0, 0, 0);
      acc[ct] = __builtin_amdgcn_mfma_f32_16x16x32_f16(al, bv, acc[ct], 0, 0, 0);
    }
  }
  __syncthreads();  // B3: all waves done reading tile — safe to alias

  // ---- cross-wave C reduction (cred aliases tile; stride 33 = conflict-free)
  float* cred = tile;
  {
    float* slot = cred + (w * 64 + lane) * 33;
#pragma unroll
    for (int ct = 0; ct < NCT; ct++)
#pragma unroll
      for (int r = 0; r < 4; r++) slot[ct * 4 + r] = acc[ct][r];
  }
  __syncthreads();  // B4

  float* ob = out + (size_t)b * 16 * COUT;
  int bk = (b & 7) * 256;
#pragma unroll
  for (int ctl = 0; ctl < 2; ctl++) {
    int ct = w * 2 + ctl;
    int co = ct * 16 + srow;
    float sp = 0.0f, qp = 0.0f;
#pragma unroll
    for (int r = 0; r < 4; r++) {
      float v = cred[lane * 33 + ct * 4 + r] +
                cred[(64 + lane) * 33 + ct * 4 + r] +
                cred[(128 + lane) * 33 + ct * 4 + r] +
                cred[(192 + lane) * 33 + ct * 4 + r];
      v = fmaxf(v, 0.0f);
      ob[((q << 2) + r) * COUT + co] = v;
      sp += v;
      qp = fmaf(v, v, qp);
    }
    sp += __shfl_xor(sp, 16, 64); sp += __shfl_xor(sp, 32, 64);
    qp += __shfl_xor(qp, 16, 64); qp += __shfl_xor(qp, 32, 64);
    if (q == 0) {
      atomicAdd(stat + bk + co, sp);
      atomicAdd(stat + bk + 128 + co, qp);
    }
  }
}

// ------------------------------------------------------------ pool + fc  (h4: [b][s][128])
__global__ __launch_bounds__(128) void k_poolfc(
    const float* __restrict__ h4, const float* __restrict__ scale,
    const float* __restrict__ shift, const float* __restrict__ fcw,
    const float* __restrict__ fcb, float* __restrict__ out) {
  __shared__ float pooled[128];
  int b = blockIdx.x;
  int c = threadIdx.x;
  const float* hb = h4 + (size_t)b * 2048;
  float sm = 0.0f;
#pragma unroll
  for (int s = 0; s < 16; s++) sm += hb[s * 128 + c];
  pooled[c] = fmaf(sm * (1.0f / 16.0f), scale[c], shift[c]);
  __syncthreads();
  if (c < 10) {
    float acc = fcb[c];
#pragma unroll
    for (int i = 0; i < 128; i++) acc = fmaf(pooled[i], fcw[c * 128 + i], acc);
    out[(size_t)b * 10 + c] = acc;
  }
}

// ---------------------------------------------------------------- launch
extern "C" void kernel_launch(void* const* d_in, const int* in_sizes, int n_in,
                              void* d_out, int out_size, void* d_ws, size_t ws_size,
                              hipStream_t stream) {
  const float* x       = (const float*)d_in[0];
  const float* conv1_w = (const float*)d_in[1];
  const float* conv1_b = (const float*)d_in[2];
  const float* bn1_g   = (const float*)d_in[3];
  const float* bn1_b   = (const float*)d_in[4];
  const float* off1_w  = (const float*)d_in[5];
  const float* off1_b  = (const float*)d_in[6];
  const float* dc1_w   = (const float*)d_in[7];
  const float* bn2_g   = (const float*)d_in[8];
  const float* bn2_b   = (const float*)d_in[9];
  const float* off2_w  = (const float*)d_in[10];
  const float* off2_b  = (const float*)d_in[11];
  const float* dc2_w   = (const float*)d_in[12];
  const float* bn3_g   = (const float*)d_in[13];
  const float* bn3_b   = (const float*)d_in[14];
  const float* off3_w  = (const float*)d_in[15];
  const float* off3_b  = (const float*)d_in[16];
  const float* dc3_w   = (const float*)d_in[17];
  const float* bn4_g   = (const float*)d_in[18];
  const float* bn4_b   = (const float*)d_in[19];
  const float* fc_w    = (const float*)d_in[20];
  const float* fc_b    = (const float*)d_in[21];
  float* out = (float*)d_out;

  float* wsf = (float*)d_ws;
  // region A: h1 [2048][256][32] / h3 [2048][64][128] alias — 16777216 floats
  float* h1 = wsf;
  float* h3 = wsf;
  // region B: h2 [2048][64][64] / h4 [2048][16][128] alias — 8388608 floats
  float* h2 = wsf + 16777216;
  float* h4 = wsf + 16777216;
  float* wbase = wsf + 25165824;
  unsigned short* wp1  = (unsigned short*)wbase;  // fp16 dc packs (239616 ushorts)
  unsigned short* wp2  = wp1 + 18432;
  unsigned short* wp3  = wp2 + 73728;
  unsigned short* w0p1 = wp3 + 147456;            // fp16 offset packs (64512 ushorts)
  unsigned short* w0p2 = w0p1 + 9216;
  unsigned short* w0p3 = w0p2 + 18432;            // 36864 ushorts
  // stats: per stage bucketed sums [8][2][128] x 4 stages, then sc/sh
  float* stat0 = wbase + 152064;                  // 304128 ushorts = 152064 floats
  float* stat1 = stat0 + 2048;
  float* stat2 = stat1 + 2048;
  float* stat3 = stat2 + 2048;
  float* scsh  = stat0 + 8192;
  float* sc1 = scsh + 0,    *sh1 = scsh + 128;
  float* sc2 = scsh + 256,  *sh2 = scsh + 384;
  float* sc3 = scsh + 512,  *sh3 = scsh + 640;
  float* sc4 = scsh + 768,  *sh4 = scsh + 896;

  hipMemsetAsync(stat0, 0, 8192 * sizeof(float), stream);
  k_prep<<<1188, 256, 0, stream>>>(dc1_w, dc2_w, dc3_w, off1_w, off2_w, off3_w,
                                   wp1, wp2, wp3, w0p1, w0p2, w0p3);

  // stage 1
  k_conv1<<<BATCH, 256, 0, stream>>>(x, conv1_w, conv1_b, h1, stat0);
  k_bnfin<<<1, 128, 0, stream>>>(stat0, bn1_g, bn1_b, sc1, sh1, 32, 1.0f / 524288.0f);
  k_dconv12<32, 16, 16, 2, 8, 8, 64, 3><<<BATCH, 256, 0, stream>>>(
      h1, sc1, sh1, w0p1, off1_b, wp1, h2, stat1);

  // stage 2
  k_bnfin<<<1, 128, 0, stream>>>(stat1, bn2_g, bn2_b, sc2, sh2, 64, 1.0f / 131072.0f);
  k_dconv12<64, 8, 8, 1, 8, 8, 128, 4><<<BATCH, 256, 0, stream>>>(
      h2, sc2, sh2, w0p2, off2_b, wp2, h3, stat2);

  // stage 3
  k_bnfin<<<1, 128, 0, stream>>>(stat2, bn3_g, bn3_b, sc3, sh3, 128, 1.0f / 131072.0f);
  k_dconv3<<<BATCH, 256, 0, stream>>>(
      h3, sc3, sh3, w0p3, off3_b, wp3, h4, stat3);

  // stage 4
  k_bnfin<<<1, 128, 0, stream>>>(stat3, bn4_g, bn4_b, sc4, sh4, 128, 1.0f / 32768.0f);
  k_poolfc<<<BATCH, 128, 0, stream>>>(h4, sc4, sh4, fc_w, fc_b, out);
}